// Round 2
// baseline (1029.199 us; speedup 1.0000x reference)
//
#include <hip/hip_runtime.h>
#include <math.h>
#include <stddef.h>

#define NHEAD 4
#define DHEAD 40
#define HIDW 160
#define JKW 320
#define NGRAPH 32

// NOTE: harness passes ALL integer inputs as int32 (reference int64 -> const int*).

// ---------------- CSR build ----------------
__global__ __launch_bounds__(256) void k_count(const int* __restrict__ dst, int E, int* __restrict__ deg){
  int e = blockIdx.x*256 + threadIdx.x;
  if (e < E) atomicAdd(&deg[dst[e]], 1);
}

__global__ __launch_bounds__(256) void k_scan1(const int* __restrict__ deg, int N, int* __restrict__ excl, int* __restrict__ bsum){
  __shared__ int s[256];
  int tid = threadIdx.x;
  int i = blockIdx.x*256 + tid;
  int v = (i < N) ? deg[i] : 0;
  s[tid] = v; __syncthreads();
  for (int off = 1; off < 256; off <<= 1){
    int t = (tid >= off) ? s[tid-off] : 0; __syncthreads();
    s[tid] += t; __syncthreads();
  }
  if (i < N) excl[i] = s[tid] - v;
  if (tid == 255) bsum[blockIdx.x] = s[255];
}

__global__ __launch_bounds__(256) void k_scan2(const int* __restrict__ bsum, int NB, int* __restrict__ boff){
  __shared__ int s[256];
  int tid = threadIdx.x;
  int v = (tid < NB) ? bsum[tid] : 0;
  s[tid] = v; __syncthreads();
  for (int off = 1; off < 256; off <<= 1){
    int t = (tid >= off) ? s[tid-off] : 0; __syncthreads();
    s[tid] += t; __syncthreads();
  }
  boff[tid] = s[tid] - v;
}

__global__ __launch_bounds__(256) void k_scan3(int* __restrict__ starts, int* __restrict__ cursor,
                                               const int* __restrict__ boff, int N, int E){
  int i = blockIdx.x*256 + threadIdx.x;
  if (i < N){
    int v = starts[i] + boff[blockIdx.x];
    starts[i] = v; cursor[i] = v;
  }
  if (i == 0) starts[N] = E;
}

__global__ __launch_bounds__(256) void k_fill(const int* __restrict__ dst, int E,
                                              int* __restrict__ cursor, int* __restrict__ eids){
  int e = blockIdx.x*256 + threadIdx.x;
  if (e < E){
    int d = dst[e];
    int p = atomicAdd(&cursor[d], 1);
    eids[p] = e;
  }
}

// ---------------- input linear ----------------
__global__ __launch_bounds__(256) void k_lin_in(const float* __restrict__ x, const float* __restrict__ W,
                                                const float* __restrict__ b, float* __restrict__ xc, int N){
  int idx = blockIdx.x*256 + threadIdx.x;
  if (idx >= N*HIDW) return;
  int n = idx / HIDW, j = idx % HIDW;
  const float* xr = x + n*5;
  float v = b[j];
  #pragma unroll
  for (int c = 0; c < 5; ++c) v += xr[c] * W[c*HIDW + j];
  xc[(size_t)n*JKW + j] = v;
}

// ---------------- weight pack for fused qkv+skip GEMM ----------------
__global__ __launch_bounds__(256) void k_pack(const float* __restrict__ Wq, const float* __restrict__ Wk,
                                              const float* __restrict__ Wv, const float* __restrict__ Ws,
                                              const float* __restrict__ bq, const float* __restrict__ bk,
                                              const float* __restrict__ bv, const float* __restrict__ bs,
                                              float* __restrict__ Bp, float* __restrict__ bp){
  int idx = blockIdx.x*256 + threadIdx.x;
  if (idx < HIDW*4*HIDW){
    int i = idx / 640, j = idx % 640;
    int sel = j / HIDW, jj = j % HIDW;
    const float* W = (sel==0) ? Wq : (sel==1) ? Wk : (sel==2) ? Wv : Ws;
    Bp[idx] = W[i*HIDW + jj];
  }
  if (idx < 640){
    int sel = idx / HIDW, jj = idx % HIDW;
    const float* bb = (sel==0) ? bq : (sel==1) ? bk : (sel==2) ? bv : bs;
    bp[idx] = bb[jj];
  }
}

// ---------------- fp32 tiled GEMM: C[M,Ncb] = A[M,K]@B[K,Ncb] + bias (opt relu) ----------------
#define KC 32
#define LDT 68
__global__ __launch_bounds__(256) void k_gemm(const float* __restrict__ A, int lda,
                                              const float* __restrict__ B, int ldb,
                                              const float* __restrict__ bias,
                                              float* __restrict__ C, int ldc,
                                              int M, int Ncb, int K, int relu){
  __shared__ float sA[KC*LDT];
  __shared__ float sB[KC*LDT];
  int tid = threadIdx.x;
  int tx = tid & 15, ty = tid >> 4;
  int row0 = blockIdx.x*64, col0 = blockIdx.y*64;
  float acc[4][4] = {{0.f}};

  for (int k0 = 0; k0 < K; k0 += KC){
    // stage A transposed: sA[k][m]
    #pragma unroll
    for (int it = 0; it < 2; ++it){
      int idx = tid + it*256;
      int m = idx >> 3, q = idx & 7;
      int r = row0 + m; if (r >= M) r = M - 1;
      float4 av = *(const float4*)(A + (size_t)r*lda + (k0 + 4*q));
      sA[(4*q+0)*LDT + m] = av.x;
      sA[(4*q+1)*LDT + m] = av.y;
      sA[(4*q+2)*LDT + m] = av.z;
      sA[(4*q+3)*LDT + m] = av.w;
    }
    // stage B: sB[k][c]
    #pragma unroll
    for (int it = 0; it < 2; ++it){
      int idx = tid + it*256;
      int kk = idx >> 4, q = idx & 15;
      int col = col0 + 4*q;
      const float* Brow = B + (size_t)(k0+kk)*ldb;
      float4 bv;
      if (col + 3 < Ncb) bv = *(const float4*)(Brow + col);
      else {
        bv.x = (col+0 < Ncb) ? Brow[col+0] : 0.f;
        bv.y = (col+1 < Ncb) ? Brow[col+1] : 0.f;
        bv.z = (col+2 < Ncb) ? Brow[col+2] : 0.f;
        bv.w = (col+3 < Ncb) ? Brow[col+3] : 0.f;
      }
      *(float4*)(&sB[kk*LDT + 4*q]) = bv;
    }
    __syncthreads();
    #pragma unroll
    for (int kk = 0; kk < KC; ++kk){
      float4 a4 = *(const float4*)(&sA[kk*LDT + 4*ty]);
      float4 b4 = *(const float4*)(&sB[kk*LDT + 4*tx]);
      float a[4] = {a4.x, a4.y, a4.z, a4.w};
      float b[4] = {b4.x, b4.y, b4.z, b4.w};
      #pragma unroll
      for (int i = 0; i < 4; ++i)
        #pragma unroll
        for (int j = 0; j < 4; ++j)
          acc[i][j] += a[i]*b[j];
    }
    __syncthreads();
  }
  #pragma unroll
  for (int i = 0; i < 4; ++i){
    int r = row0 + 4*ty + i;
    if (r >= M) continue;
    #pragma unroll
    for (int j = 0; j < 4; ++j){
      int c = col0 + 4*tx + j;
      if (c >= Ncb) continue;
      float v = acc[i][j] + bias[c];
      if (relu) v = fmaxf(v, 0.f);
      C[(size_t)r*ldc + c] = v;
    }
  }
}

// ---------------- fused edge attention (per-dst-node, online softmax) ----------------
// wave of 64 = 4 edge-groups x (4 heads x 4 lanes); lane covers 10 consecutive dims of its head
__global__ __launch_bounds__(256) void k_attn(const float* __restrict__ qkvr, const float* __restrict__ edge_attr,
                                              const int* __restrict__ src, const int* __restrict__ starts,
                                              const int* __restrict__ eids, const float* __restrict__ We,
                                              const float* __restrict__ be, float* __restrict__ attout, int N){
  int n = blockIdx.x*4 + (threadIdx.x >> 6);
  if (n >= N) return;                 // wave-uniform exit
  int lane = threadIdx.x & 63;
  int g4 = lane >> 4;                 // edge slot within wave
  int w  = lane & 15;
  int h  = w & 3, t = w >> 2;
  int cbase = DHEAD*h + 10*t;
  const float scale = 0.15811388300841898f;  // 1/sqrt(40)

  float qs[10];
  #pragma unroll
  for (int j = 0; j < 10; ++j) qs[j] = qkvr[(size_t)n*640 + cbase + j] * scale;

  float m = -INFINITY, ssum = 0.f;
  float acc[10];
  #pragma unroll
  for (int j = 0; j < 10; ++j) acc[j] = 0.f;

  int s0 = starts[n], s1 = starts[n+1];
  for (int base = s0; base < s1; base += 4){
    int epos = base + g4;
    if (epos < s1){
      int eid = eids[epos];
      int sn = src[eid];
      float ea0 = edge_attr[(size_t)eid*4+0], ea1 = edge_attr[(size_t)eid*4+1];
      float ea2 = edge_attr[(size_t)eid*4+2], ea3 = edge_attr[(size_t)eid*4+3];
      const float* kp = qkvr + (size_t)sn*640 + 160 + cbase;
      const float* vp = qkvr + (size_t)sn*640 + 320 + cbase;
      float ec[10];
      float p = 0.f;
      #pragma unroll
      for (int j = 0; j < 10; ++j){
        int c = cbase + j;
        ec[j] = be[c] + ea0*We[c] + ea1*We[160+c] + ea2*We[320+c] + ea3*We[480+c];
        p += qs[j] * (kp[j] + ec[j]);
      }
      p += __shfl_xor(p, 4);
      p += __shfl_xor(p, 8);
      float mnew = fmaxf(m, p);
      float fac = expf(m - mnew);    // m=-inf on first edge -> 0
      float ex  = expf(p - mnew);
      ssum = ssum*fac + ex;
      #pragma unroll
      for (int j = 0; j < 10; ++j) acc[j] = acc[j]*fac + ex*(vp[j] + ec[j]);
      m = mnew;
    }
  }

  // merge the 4 edge-groups (lanes xor 16, 32)
  #pragma unroll
  for (int xm = 16; xm < 64; xm <<= 1){
    float mo = __shfl_xor(m, xm);
    float so = __shfl_xor(ssum, xm);
    float ao[10];
    #pragma unroll
    for (int j = 0; j < 10; ++j) ao[j] = __shfl_xor(acc[j], xm);
    float M2 = fmaxf(m, mo);
    float f1 = (m  == -INFINITY) ? 0.f : expf(m  - M2);
    float f2 = (mo == -INFINITY) ? 0.f : expf(mo - M2);
    ssum = ssum*f1 + so*f2;
    #pragma unroll
    for (int j = 0; j < 10; ++j) acc[j] = acc[j]*f1 + ao[j]*f2;
    m = M2;
  }
  if (g4 == 0){
    float inv = (ssum > 0.f) ? 1.f/ssum : 0.f;
    #pragma unroll
    for (int j = 0; j < 10; ++j) attout[(size_t)n*160 + cbase + j] = acc[j]*inv;
  }
}

// ---------------- beta gate + combine, writes h into xc slice ----------------
__global__ __launch_bounds__(256) void k_beta(const float* __restrict__ qkvr, const float* __restrict__ attout,
                                              const float* __restrict__ Wb, float* __restrict__ xc,
                                              int loff, int N){
  int n = blockIdx.x*4 + (threadIdx.x >> 6);
  if (n >= N) return;
  int lane = threadIdx.x & 63;
  float o0 = attout[(size_t)n*160 + lane];
  float o1 = attout[(size_t)n*160 + 64 + lane];
  float r0 = qkvr[(size_t)n*640 + 480 + lane];
  float r1 = qkvr[(size_t)n*640 + 480 + 64 + lane];
  float o2 = 0.f, r2 = 0.f;
  float p = o0*Wb[lane] + o1*Wb[64+lane]
          + r0*Wb[160+lane] + r1*Wb[160+64+lane]
          + (o0-r0)*Wb[320+lane] + (o1-r1)*Wb[320+64+lane];
  if (lane < 32){
    o2 = attout[(size_t)n*160 + 128 + lane];
    r2 = qkvr[(size_t)n*640 + 480 + 128 + lane];
    p += o2*Wb[128+lane] + r2*Wb[160+128+lane] + (o2-r2)*Wb[320+128+lane];
  }
  #pragma unroll
  for (int xm = 1; xm < 64; xm <<= 1) p += __shfl_xor(p, xm);
  float beta = 1.f/(1.f + expf(-p));
  float* dstp = xc + (size_t)n*JKW + loff;
  dstp[lane]      = beta*r0 + (1.f-beta)*o0;
  dstp[64+lane]   = beta*r1 + (1.f-beta)*o1;
  if (lane < 32) dstp[128+lane] = beta*r2 + (1.f-beta)*o2;
}

// ---------------- gate scalar: gate[n] = tmp[n,:]·Wg2 + bg2 ----------------
__global__ __launch_bounds__(256) void k_gate(const float* __restrict__ tmp, const float* __restrict__ Wg2,
                                              const float* __restrict__ bg2, float* __restrict__ gate, int N){
  int n = blockIdx.x*4 + (threadIdx.x >> 6);
  if (n >= N) return;
  int lane = threadIdx.x & 63;
  float p = tmp[(size_t)n*160 + lane]*Wg2[lane] + tmp[(size_t)n*160 + 64 + lane]*Wg2[64+lane];
  if (lane < 32) p += tmp[(size_t)n*160 + 128 + lane]*Wg2[128+lane];
  #pragma unroll
  for (int xm = 1; xm < 64; xm <<= 1) p += __shfl_xor(p, xm);
  if (lane == 0) gate[n] = p + bg2[0];
}

// ---------------- graph boundaries (batch is sorted) ----------------
__global__ __launch_bounds__(256) void k_gbound(const int* __restrict__ batch, int N, int* __restrict__ gs){
  int i = blockIdx.x*256 + threadIdx.x;
  if (i >= N) return;
  int g = batch[i];
  int prev = (i == 0) ? -1 : batch[i-1];
  for (int gg = prev+1; gg <= g; ++gg) gs[gg] = i;
  if (i == N-1){ for (int gg = g+1; gg <= NGRAPH; ++gg) gs[gg] = N; }
}

// ---------------- per-graph softmax stats ----------------
__global__ __launch_bounds__(256) void k_gstat(const float* __restrict__ gate, const int* __restrict__ gs,
                                               float* __restrict__ gmax, float* __restrict__ gden){
  __shared__ float sm[256];
  int g = blockIdx.x, tid = threadIdx.x;
  int lo = gs[g], hi = gs[g+1];
  float m = -INFINITY;
  for (int i = lo + tid; i < hi; i += 256) m = fmaxf(m, gate[i]);
  sm[tid] = m; __syncthreads();
  for (int off = 128; off; off >>= 1){ if (tid < off) sm[tid] = fmaxf(sm[tid], sm[tid+off]); __syncthreads(); }
  float M = sm[0]; __syncthreads();
  float s = 0.f;
  for (int i = lo + tid; i < hi; i += 256) s += expf(gate[i] - M);
  sm[tid] = s; __syncthreads();
  for (int off = 128; off; off >>= 1){ if (tid < off) sm[tid] += sm[tid+off]; __syncthreads(); }
  if (tid == 0){ gmax[g] = M; gden[g] = sm[0]; }
}

__global__ __launch_bounds__(256) void k_att(const float* __restrict__ gate, const int* __restrict__ batch,
                                             const float* __restrict__ gmax, const float* __restrict__ gden,
                                             float* __restrict__ att, int N){
  int i = blockIdx.x*256 + threadIdx.x;
  if (i >= N) return;
  int g = batch[i];
  float d = gden[g];
  att[i] = (d > 0.f) ? expf(gate[i] - gmax[g])/d : 0.f;
}

// ---------------- attention pooling: pooled[g,j] = sum att[n]*xc[n,j] ----------------
__global__ __launch_bounds__(320) void k_pool(const float* __restrict__ xc, const float* __restrict__ att,
                                              const int* __restrict__ gs, float* __restrict__ pooled){
  int g = blockIdx.x, part = blockIdx.y, j = threadIdx.x;
  int lo = gs[g], hi = gs[g+1];
  int len = hi - lo;
  if (len <= 0) return;
  int chunk = (len + (int)gridDim.y - 1) / (int)gridDim.y;
  int a = lo + part*chunk;
  int bnd = a + chunk; if (bnd > hi) bnd = hi;
  if (a >= bnd) return;
  float s = 0.f;
  for (int n = a; n < bnd; ++n) s += att[n]*xc[(size_t)n*JKW + j];
  atomicAdd(&pooled[g*JKW + j], s);
}

// ---------------- head MLP (tiny) ----------------
__global__ __launch_bounds__(320) void k_head(const float* __restrict__ pooled, const float* __restrict__ Wh1,
                                              const float* __restrict__ bh1, const float* __restrict__ Wh2,
                                              const float* __restrict__ bh2, float* __restrict__ out){
  __shared__ float p[320];
  __shared__ float t[320];
  int g = blockIdx.x, tid = threadIdx.x;
  p[tid] = pooled[g*JKW + tid]; __syncthreads();
  float a = bh1[tid];
  for (int i = 0; i < 320; ++i) a += p[i]*Wh1[i*JKW + tid];
  t[tid] = fmaxf(a, 0.f); __syncthreads();
  if (tid < 6){
    float o = bh2[tid];
    for (int j = 0; j < 320; ++j) o += t[j]*Wh2[j*6 + tid];
    out[g*6 + tid] = o;
  }
}

extern "C" void kernel_launch(void* const* d_in, const int* in_sizes, int n_in,
                              void* d_out, int out_size, void* d_ws, size_t ws_size,
                              hipStream_t stream){
  (void)n_in; (void)out_size; (void)ws_size;
  const float* x        = (const float*)d_in[0];
  const int*   eidx     = (const int*)d_in[1];     // int64 in reference -> int32 from harness
  const float* edge_attr= (const float*)d_in[2];
  const int*   batch    = (const int*)d_in[3];     // int64 in reference -> int32 from harness
  const float* W_in     = (const float*)d_in[4];
  const float* b_in     = (const float*)d_in[5];
  const float* Wq       = (const float*)d_in[6];
  const float* bq       = (const float*)d_in[7];
  const float* Wk       = (const float*)d_in[8];
  const float* bk       = (const float*)d_in[9];
  const float* Wv       = (const float*)d_in[10];
  const float* bv       = (const float*)d_in[11];
  const float* We       = (const float*)d_in[12];
  const float* be       = (const float*)d_in[13];
  const float* Wsk      = (const float*)d_in[14];
  const float* bsk      = (const float*)d_in[15];
  const float* Wb       = (const float*)d_in[16];
  const float* Wg1      = (const float*)d_in[17];
  const float* bg1      = (const float*)d_in[18];
  const float* Wg2      = (const float*)d_in[19];
  const float* bg2      = (const float*)d_in[20];
  const float* Wh1      = (const float*)d_in[21];
  const float* bh1      = (const float*)d_in[22];
  const float* Wh2      = (const float*)d_in[23];
  const float* bh2      = (const float*)d_in[24];

  const int N = in_sizes[0] / 5;
  const int E = in_sizes[1] / 2;
  float* out = (float*)d_out;

  // workspace layout
  char* w = (char*)d_ws;
  auto alloc = [&](size_t bytes)->char*{ char* p = w; w += (bytes + 255) & ~(size_t)255; return p; };
  float* xc     = (float*)alloc((size_t)N*JKW*4);     // [N,320]; h0/h1 live in cols 0..159
  float* qkvr   = (float*)alloc((size_t)N*640*4);     // q|k|v|r
  float* attout = (float*)alloc((size_t)N*HIDW*4);    // attention out; reused as gate-GEMM tmp
  float* Bpack  = (float*)alloc((size_t)HIDW*640*4);
  float* bpack  = (float*)alloc(640*4);
  int*   deg    = (int*)alloc((size_t)N*4);
  int*   starts = (int*)alloc((size_t)(N+1)*4);
  int*   cursor = (int*)alloc((size_t)(N+1)*4);
  int*   eids   = (int*)alloc((size_t)E*4);
  const int NB  = (N + 255)/256;
  int*   bsum   = (int*)alloc((size_t)NB*4);
  int*   boff   = (int*)alloc(256*4);
  float* gate   = (float*)alloc((size_t)N*4);
  float* attg   = (float*)alloc((size_t)N*4);
  int*   gs     = (int*)alloc((NGRAPH+1)*4);
  float* gmax   = (float*)alloc(NGRAPH*4);
  float* gden   = (float*)alloc(NGRAPH*4);
  float* pooled = (float*)alloc(NGRAPH*JKW*4);

  const int* srcI = eidx;
  const int* dstI = eidx + E;

  hipMemsetAsync(deg, 0, (size_t)N*4, stream);
  hipMemsetAsync(pooled, 0, (size_t)NGRAPH*JKW*4, stream);

  const int eb = (E + 255)/256;
  k_count<<<eb, 256, 0, stream>>>(dstI, E, deg);
  k_scan1<<<NB, 256, 0, stream>>>(deg, N, starts, bsum);
  k_scan2<<<1, 256, 0, stream>>>(bsum, NB, boff);
  k_scan3<<<NB, 256, 0, stream>>>(starts, cursor, boff, N, E);
  k_fill<<<eb, 256, 0, stream>>>(dstI, E, cursor, eids);

  k_lin_in<<<(N*HIDW + 255)/256, 256, 0, stream>>>(x, W_in, b_in, xc, N);

  for (int l = 0; l < 2; ++l){
    k_pack<<<400, 256, 0, stream>>>(Wq + l*25600, Wk + l*25600, Wv + l*25600, Wsk + l*25600,
                                    bq + l*160, bk + l*160, bv + l*160, bsk + l*160, Bpack, bpack);
    dim3 g1((N + 63)/64, 10);
    k_gemm<<<g1, 256, 0, stream>>>(xc, JKW, Bpack, 640, bpack, qkvr, 640, N, 640, HIDW, 0);
    k_attn<<<(N + 3)/4, 256, 0, stream>>>(qkvr, edge_attr, srcI, starts, eids,
                                          We + l*640, be + l*160, attout, N);
    k_beta<<<(N + 3)/4, 256, 0, stream>>>(qkvr, attout, Wb + l*480, xc, l*HIDW, N);
  }

  // gate MLP: tmp = relu(xc@Wg1+bg1) in attout; gate[n] = tmp·Wg2 + bg2
  dim3 g2((N + 63)/64, 3);
  k_gemm<<<g2, 256, 0, stream>>>(xc, JKW, Wg1, HIDW, bg1, attout, HIDW, N, HIDW, JKW, 1);
  k_gate<<<(N + 3)/4, 256, 0, stream>>>(attout, Wg2, bg2, gate, N);

  k_gbound<<<(N + 255)/256, 256, 0, stream>>>(batch, N, gs);
  k_gstat<<<NGRAPH, 256, 0, stream>>>(gate, gs, gmax, gden);
  k_att<<<(N + 255)/256, 256, 0, stream>>>(gate, batch, gmax, gden, attg, N);
  dim3 g3(NGRAPH, 8);
  k_pool<<<g3, 320, 0, stream>>>(xc, attg, gs, pooled);
  k_head<<<NGRAPH, 320, 0, stream>>>(pooled, Wh1, bh1, Wh2, bh2, out);
}

// Round 3
// 947.244 us; speedup vs baseline: 1.0865x; 1.0865x over previous
//
#include <hip/hip_runtime.h>
#include <math.h>
#include <stddef.h>

#define NHEAD 4
#define DHEAD 40
#define HIDW 160
#define JKW 320
#define NGRAPH 32

typedef __attribute__((ext_vector_type(8))) short short8;
typedef __attribute__((ext_vector_type(4))) float f32x4;

__device__ inline unsigned short f2bf(float x){
  unsigned u = __float_as_uint(x);
  u += 0x7fff + ((u >> 16) & 1);
  return (unsigned short)(u >> 16);
}
__device__ inline float bf2f(unsigned short h){
  return __uint_as_float(((unsigned)h) << 16);
}

// ---------------- CSR build ----------------
__global__ __launch_bounds__(256) void k_count(const int* __restrict__ dst, int E, int* __restrict__ deg){
  int e = blockIdx.x*256 + threadIdx.x;
  if (e < E) atomicAdd(&deg[dst[e]], 1);
}

__global__ __launch_bounds__(256) void k_scan1(const int* __restrict__ deg, int N, int* __restrict__ excl, int* __restrict__ bsum){
  __shared__ int s[256];
  int tid = threadIdx.x;
  int i = blockIdx.x*256 + tid;
  int v = (i < N) ? deg[i] : 0;
  s[tid] = v; __syncthreads();
  for (int off = 1; off < 256; off <<= 1){
    int t = (tid >= off) ? s[tid-off] : 0; __syncthreads();
    s[tid] += t; __syncthreads();
  }
  if (i < N) excl[i] = s[tid] - v;
  if (tid == 255) bsum[blockIdx.x] = s[255];
}

__global__ __launch_bounds__(256) void k_scan2(const int* __restrict__ bsum, int NB, int* __restrict__ boff){
  __shared__ int s[256];
  int tid = threadIdx.x;
  int v = (tid < NB) ? bsum[tid] : 0;
  s[tid] = v; __syncthreads();
  for (int off = 1; off < 256; off <<= 1){
    int t = (tid >= off) ? s[tid-off] : 0; __syncthreads();
    s[tid] += t; __syncthreads();
  }
  boff[tid] = s[tid] - v;
}

__global__ __launch_bounds__(256) void k_scan3(int* __restrict__ starts, int* __restrict__ cursor,
                                               const int* __restrict__ boff, int N, int E){
  int i = blockIdx.x*256 + threadIdx.x;
  if (i < N){
    int v = starts[i] + boff[blockIdx.x];
    starts[i] = v; cursor[i] = v;
  }
  if (i == 0) starts[N] = E;
}

// fill CSR with src node id and edge_attr reordered into CSR position (kills one indirection level in attn)
__global__ __launch_bounds__(256) void k_fill(const int* __restrict__ dst, const int* __restrict__ src,
                                              const float* __restrict__ edge_attr, int E,
                                              int* __restrict__ cursor, int* __restrict__ esrc,
                                              float4* __restrict__ eattr){
  int e = blockIdx.x*256 + threadIdx.x;
  if (e < E){
    int d = dst[e];
    int p = atomicAdd(&cursor[d], 1);
    esrc[p] = src[e];
    eattr[p] = *(const float4*)(edge_attr + (size_t)e*4);
  }
}

// ---------------- input linear ----------------
__global__ __launch_bounds__(256) void k_lin_in(const float* __restrict__ x, const float* __restrict__ W,
                                                const float* __restrict__ b, float* __restrict__ xc, int N){
  int idx = blockIdx.x*256 + threadIdx.x;
  if (idx >= N*HIDW) return;
  int n = idx / HIDW, j = idx % HIDW;
  const float* xr = x + n*5;
  float v = b[j];
  #pragma unroll
  for (int c = 0; c < 5; ++c) v += xr[c] * W[c*HIDW + j];
  xc[(size_t)n*JKW + j] = v;
}

// ---------------- weight pack: fused QKV+skip -> transposed split-bf16 Bt[640][160] ----------------
__global__ __launch_bounds__(256) void k_wpack(const float* __restrict__ Wq, const float* __restrict__ Wk,
                                               const float* __restrict__ Wv, const float* __restrict__ Ws,
                                               const float* __restrict__ bq, const float* __restrict__ bk,
                                               const float* __restrict__ bv, const float* __restrict__ bs,
                                               unsigned short* __restrict__ Bth, unsigned short* __restrict__ Btl,
                                               float* __restrict__ bp){
  int idx = blockIdx.x*256 + threadIdx.x;
  if (idx < 640*160){
    int j = idx / 160, i = idx % 160;       // j = output col (0..640), i = k (0..160)
    int sel = j / HIDW, jj = j % HIDW;
    const float* W = (sel==0) ? Wq : (sel==1) ? Wk : (sel==2) ? Wv : Ws;
    float v = W[i*HIDW + jj];
    unsigned short h = f2bf(v);
    Bth[(size_t)j*160 + i] = h;
    Btl[(size_t)j*160 + i] = f2bf(v - bf2f(h));
  }
  if (idx < 640){
    int sel = idx / HIDW, jj = idx % HIDW;
    const float* bb = (sel==0) ? bq : (sel==1) ? bk : (sel==2) ? bv : bs;
    bp[idx] = bb[jj];
  }
}

// gate weight: Wg1[320][160] -> Bt[160][320] split-bf16
__global__ __launch_bounds__(256) void k_wpack_gate(const float* __restrict__ Wg1,
                                                    unsigned short* __restrict__ Bth, unsigned short* __restrict__ Btl){
  int idx = blockIdx.x*256 + threadIdx.x;
  if (idx >= 160*320) return;
  int j = idx / 320, i = idx % 320;          // j = output col (0..160), i = k (0..320)
  float v = Wg1[(size_t)i*160 + j];
  unsigned short h = f2bf(v);
  Bth[(size_t)j*320 + i] = h;
  Btl[(size_t)j*320 + i] = f2bf(v - bf2f(h));
}

// ---------------- split-bf16 MFMA GEMM ----------------
// C[M,*] = A[M,K](fp32, lda) @ B  with B given transposed+split bf16: Bt[col][K].
// hi/lo decomposition: A*B ~= Ah*Bh + Al*Bh + Ah*Bl  (rel err ~1e-5)
// wave tile: 16 rows x (16*NSUB) cols; block = 4 waves stacked in M.
template<int NSUB, int RELU>
__global__ __launch_bounds__(256) void k_mgemm(const float* __restrict__ A, int lda,
                                               const unsigned short* __restrict__ Bh,
                                               const unsigned short* __restrict__ Bl,
                                               const float* __restrict__ bias,
                                               float* __restrict__ C, int ldc,
                                               int M, int K){
  int wv = threadIdx.x >> 6, lane = threadIdx.x & 63;
  int quad = lane >> 4, l16 = lane & 15;
  int m0 = blockIdx.x*64 + wv*16;
  int col0 = blockIdx.y * (16*NSUB);
  int arow = m0 + l16; if (arow >= M) arow = M - 1;
  const float* Ap = A + (size_t)arow*lda + quad*8;

  f32x4 acc[NSUB];
  #pragma unroll
  for (int s = 0; s < NSUB; ++s) acc[s] = (f32x4){0.f,0.f,0.f,0.f};

  for (int k0 = 0; k0 < K; k0 += 32){
    float4 a0 = *(const float4*)(Ap + k0);
    float4 a1 = *(const float4*)(Ap + k0 + 4);
    float av[8] = {a0.x,a0.y,a0.z,a0.w,a1.x,a1.y,a1.z,a1.w};
    short8 ah, al;
    #pragma unroll
    for (int j = 0; j < 8; ++j){
      unsigned short h = f2bf(av[j]);
      ah[j] = (short)h;
      al[j] = (short)f2bf(av[j] - bf2f(h));
    }
    #pragma unroll
    for (int s = 0; s < NSUB; ++s){
      size_t boff = (size_t)(col0 + s*16 + l16)*K + k0 + quad*8;
      short8 bh = *(const short8*)(Bh + boff);
      short8 bl = *(const short8*)(Bl + boff);
      acc[s] = __builtin_amdgcn_mfma_f32_16x16x32_bf16(ah, bh, acc[s], 0, 0, 0);
      acc[s] = __builtin_amdgcn_mfma_f32_16x16x32_bf16(al, bh, acc[s], 0, 0, 0);
      acc[s] = __builtin_amdgcn_mfma_f32_16x16x32_bf16(ah, bl, acc[s], 0, 0, 0);
    }
  }
  // C/D layout: col = lane&15, row = quad*4 + reg
  #pragma unroll
  for (int s = 0; s < NSUB; ++s){
    int col = col0 + s*16 + l16;
    float bv = bias ? bias[col] : 0.f;
    #pragma unroll
    for (int r = 0; r < 4; ++r){
      int row = m0 + quad*4 + r;
      if (row < M){
        float v = acc[s][r] + bv;
        if (RELU) v = fmaxf(v, 0.f);
        C[(size_t)row*ldc + col] = v;
      }
    }
  }
}

// ---------------- fused edge attention + beta gate (per-dst-node, online softmax) ----------------
// wave = 4 edge-slots x (4 heads x 4 lanes); lane covers 10 dims of its head.
// score: q.(k+e) = q.k + qb + ea.qw   (qw/qb per-node precompute)
// out  : inv*acc + (inv*sacc_i)*We_i + be   (We lift once per node)
__global__ __launch_bounds__(256) void k_attn(const float* __restrict__ qkvr,
                                              const float4* __restrict__ eattr,
                                              const int* __restrict__ esrc,
                                              const int* __restrict__ starts,
                                              const float* __restrict__ We, const float* __restrict__ be,
                                              const float* __restrict__ Wb,
                                              float* __restrict__ xc, int loff, int N){
  int n = blockIdx.x*4 + (threadIdx.x >> 6);
  if (n >= N) return;
  int lane = threadIdx.x & 63;
  int g4 = lane >> 4;
  int w  = lane & 15;
  int hh = w & 3, t = w >> 2;
  int cbase = DHEAD*hh + 10*t;
  const float scale = 0.15811388300841898f;  // 1/sqrt(40)

  float qs[10];
  const float* qp = qkvr + (size_t)n*640 + cbase;
  #pragma unroll
  for (int j = 0; j < 10; ++j) qs[j] = qp[j] * scale;

  // per-node: qw[i] = q_head . We[i, head-dims], qb = q_head . be[head-dims]
  float qw0=0.f,qw1=0.f,qw2=0.f,qw3=0.f,qb=0.f;
  #pragma unroll
  for (int j = 0; j < 10; ++j){
    int c = cbase + j;
    qw0 += qs[j]*We[c];     qw1 += qs[j]*We[160+c];
    qw2 += qs[j]*We[320+c]; qw3 += qs[j]*We[480+c];
    qb  += qs[j]*be[c];
  }
  // reduce over the 4 t-lanes of the head (xor 4, 8)
  qw0 += __shfl_xor(qw0,4); qw0 += __shfl_xor(qw0,8);
  qw1 += __shfl_xor(qw1,4); qw1 += __shfl_xor(qw1,8);
  qw2 += __shfl_xor(qw2,4); qw2 += __shfl_xor(qw2,8);
  qw3 += __shfl_xor(qw3,4); qw3 += __shfl_xor(qw3,8);
  qb  += __shfl_xor(qb ,4); qb  += __shfl_xor(qb ,8);

  float m = -INFINITY, ssum = 0.f;
  float acc[10];
  #pragma unroll
  for (int j = 0; j < 10; ++j) acc[j] = 0.f;
  float sa0=0.f, sa1=0.f, sa2=0.f, sa3=0.f;

  int st = starts[n], en = starts[n+1];
  // pipeline stage: ids+attr and k/v for the first batch
  int epos = st + g4;
  bool valid = (epos < en);
  int sn = 0; float4 ea = make_float4(0.f,0.f,0.f,0.f);
  if (valid){ sn = esrc[epos]; ea = eattr[epos]; }
  float kreg[10], vreg[10];
  if (valid){
    const float* kp = qkvr + (size_t)sn*640 + 160 + cbase;
    #pragma unroll
    for (int j = 0; j < 10; ++j){ kreg[j] = kp[j]; vreg[j] = kp[160+j]; }
  }

  for (int base = st; base < en; base += 4){
    bool cvalid = valid;
    float4 cea = ea;
    float ck[10], cv[10];
    #pragma unroll
    for (int j = 0; j < 10; ++j){ ck[j] = kreg[j]; cv[j] = vreg[j]; }

    // prefetch next batch ids/attr
    int np = base + 4 + g4;
    valid = (np < en);
    if (valid){ sn = esrc[np]; ea = eattr[np]; }

    // score for current batch
    float p = 0.f;
    if (cvalid){
      #pragma unroll
      for (int j = 0; j < 10; ++j) p += qs[j]*ck[j];
    }
    p += __shfl_xor(p, 4);
    p += __shfl_xor(p, 8);
    p += qb + cea.x*qw0 + cea.y*qw1 + cea.z*qw2 + cea.w*qw3;

    if (cvalid){
      float mnew = fmaxf(m, p);
      float fac = expf(m - mnew);
      float ex  = expf(p - mnew);
      ssum = ssum*fac + ex;
      #pragma unroll
      for (int j = 0; j < 10; ++j) acc[j] = acc[j]*fac + ex*cv[j];
      sa0 = sa0*fac + ex*cea.x; sa1 = sa1*fac + ex*cea.y;
      sa2 = sa2*fac + ex*cea.z; sa3 = sa3*fac + ex*cea.w;
      m = mnew;
    }

    // prefetch next batch k/v
    if (valid){
      const float* kp = qkvr + (size_t)sn*640 + 160 + cbase;
      #pragma unroll
      for (int j = 0; j < 10; ++j){ kreg[j] = kp[j]; vreg[j] = kp[160+j]; }
    }
  }

  // merge the 4 edge-slots (xor 16, 32)
  #pragma unroll
  for (int xm = 16; xm < 64; xm <<= 1){
    float mo = __shfl_xor(m, xm);
    float so = __shfl_xor(ssum, xm);
    float ao[10];
    #pragma unroll
    for (int j = 0; j < 10; ++j) ao[j] = __shfl_xor(acc[j], xm);
    float t0 = __shfl_xor(sa0, xm), t1 = __shfl_xor(sa1, xm);
    float t2 = __shfl_xor(sa2, xm), t3 = __shfl_xor(sa3, xm);
    float M2 = fmaxf(m, mo);
    float f1 = (m  == -INFINITY) ? 0.f : expf(m  - M2);
    float f2 = (mo == -INFINITY) ? 0.f : expf(mo - M2);
    ssum = ssum*f1 + so*f2;
    #pragma unroll
    for (int j = 0; j < 10; ++j) acc[j] = acc[j]*f1 + ao[j]*f2;
    sa0 = sa0*f1 + t0*f2; sa1 = sa1*f1 + t1*f2;
    sa2 = sa2*f1 + t2*f2; sa3 = sa3*f1 + t3*f2;
    m = M2;
  }

  float inv = (ssum > 0.f) ? 1.f/ssum : 0.f;
  float w0 = sa0*inv, w1 = sa1*inv, w2 = sa2*inv, w3 = sa3*inv;
  float bterm = (ssum > 0.f) ? 1.f : 0.f;
  float outv[10], rr[10];
  const float* rp = qkvr + (size_t)n*640 + 480 + cbase;
  #pragma unroll
  for (int j = 0; j < 10; ++j){
    int c = cbase + j;
    outv[j] = acc[j]*inv + w0*We[c] + w1*We[160+c] + w2*We[320+c] + w3*We[480+c] + bterm*be[c];
    rr[j] = rp[j];
  }
  // fused beta gate
  float part = 0.f;
  if (g4 == 0){
    #pragma unroll
    for (int j = 0; j < 10; ++j){
      int c = cbase + j;
      part += outv[j]*Wb[c] + rr[j]*Wb[160+c] + (outv[j]-rr[j])*Wb[320+c];
    }
  }
  #pragma unroll
  for (int xm = 1; xm < 64; xm <<= 1) part += __shfl_xor(part, xm);
  float beta = 1.f/(1.f + expf(-part));
  if (g4 == 0){
    float* dp = xc + (size_t)n*JKW + loff + cbase;
    #pragma unroll
    for (int j = 0; j < 10; ++j) dp[j] = beta*rr[j] + (1.f-beta)*outv[j];
  }
}

// ---------------- gate scalar ----------------
__global__ __launch_bounds__(256) void k_gate(const float* __restrict__ tmp, const float* __restrict__ Wg2,
                                              const float* __restrict__ bg2, float* __restrict__ gate, int N){
  int n = blockIdx.x*4 + (threadIdx.x >> 6);
  if (n >= N) return;
  int lane = threadIdx.x & 63;
  float p = tmp[(size_t)n*160 + lane]*Wg2[lane] + tmp[(size_t)n*160 + 64 + lane]*Wg2[64+lane];
  if (lane < 32) p += tmp[(size_t)n*160 + 128 + lane]*Wg2[128+lane];
  #pragma unroll
  for (int xm = 1; xm < 64; xm <<= 1) p += __shfl_xor(p, xm);
  if (lane == 0) gate[n] = p + bg2[0];
}

// ---------------- graph boundaries ----------------
__global__ __launch_bounds__(256) void k_gbound(const int* __restrict__ batch, int N, int* __restrict__ gs){
  int i = blockIdx.x*256 + threadIdx.x;
  if (i >= N) return;
  int g = batch[i];
  int prev = (i == 0) ? -1 : batch[i-1];
  for (int gg = prev+1; gg <= g; ++gg) gs[gg] = i;
  if (i == N-1){ for (int gg = g+1; gg <= NGRAPH; ++gg) gs[gg] = N; }
}

__global__ __launch_bounds__(256) void k_gstat(const float* __restrict__ gate, const int* __restrict__ gs,
                                               float* __restrict__ gmax, float* __restrict__ gden){
  __shared__ float sm[256];
  int g = blockIdx.x, tid = threadIdx.x;
  int lo = gs[g], hi = gs[g+1];
  float m = -INFINITY;
  for (int i = lo + tid; i < hi; i += 256) m = fmaxf(m, gate[i]);
  sm[tid] = m; __syncthreads();
  for (int off = 128; off; off >>= 1){ if (tid < off) sm[tid] = fmaxf(sm[tid], sm[tid+off]); __syncthreads(); }
  float M = sm[0]; __syncthreads();
  float s = 0.f;
  for (int i = lo + tid; i < hi; i += 256) s += expf(gate[i] - M);
  sm[tid] = s; __syncthreads();
  for (int off = 128; off; off >>= 1){ if (tid < off) sm[tid] += sm[tid+off]; __syncthreads(); }
  if (tid == 0){ gmax[g] = M; gden[g] = sm[0]; }
}

__global__ __launch_bounds__(256) void k_att(const float* __restrict__ gate, const int* __restrict__ batch,
                                             const float* __restrict__ gmax, const float* __restrict__ gden,
                                             float* __restrict__ att, int N){
  int i = blockIdx.x*256 + threadIdx.x;
  if (i >= N) return;
  int g = batch[i];
  float d = gden[g];
  att[i] = (d > 0.f) ? expf(gate[i] - gmax[g])/d : 0.f;
}

__global__ __launch_bounds__(320) void k_pool(const float* __restrict__ xc, const float* __restrict__ att,
                                              const int* __restrict__ gs, float* __restrict__ pooled){
  int g = blockIdx.x, part = blockIdx.y, j = threadIdx.x;
  int lo = gs[g], hi = gs[g+1];
  int len = hi - lo;
  if (len <= 0) return;
  int chunk = (len + (int)gridDim.y - 1) / (int)gridDim.y;
  int a = lo + part*chunk;
  int bnd = a + chunk; if (bnd > hi) bnd = hi;
  if (a >= bnd) return;
  float s = 0.f;
  for (int n = a; n < bnd; ++n) s += att[n]*xc[(size_t)n*JKW + j];
  atomicAdd(&pooled[g*JKW + j], s);
}

__global__ __launch_bounds__(320) void k_head(const float* __restrict__ pooled, const float* __restrict__ Wh1,
                                              const float* __restrict__ bh1, const float* __restrict__ Wh2,
                                              const float* __restrict__ bh2, float* __restrict__ out){
  __shared__ float p[320];
  __shared__ float t[320];
  int g = blockIdx.x, tid = threadIdx.x;
  p[tid] = pooled[g*JKW + tid]; __syncthreads();
  float a = bh1[tid];
  for (int i = 0; i < 320; ++i) a += p[i]*Wh1[i*JKW + tid];
  t[tid] = fmaxf(a, 0.f); __syncthreads();
  if (tid < 6){
    float o = bh2[tid];
    for (int j = 0; j < 320; ++j) o += t[j]*Wh2[j*6 + tid];
    out[g*6 + tid] = o;
  }
}

extern "C" void kernel_launch(void* const* d_in, const int* in_sizes, int n_in,
                              void* d_out, int out_size, void* d_ws, size_t ws_size,
                              hipStream_t stream){
  (void)n_in; (void)out_size; (void)ws_size;
  const float* x        = (const float*)d_in[0];
  const int*   eidx     = (const int*)d_in[1];
  const float* edge_attr= (const float*)d_in[2];
  const int*   batch    = (const int*)d_in[3];
  const float* W_in     = (const float*)d_in[4];
  const float* b_in     = (const float*)d_in[5];
  const float* Wq       = (const float*)d_in[6];
  const float* bq       = (const float*)d_in[7];
  const float* Wk       = (const float*)d_in[8];
  const float* bk       = (const float*)d_in[9];
  const float* Wv       = (const float*)d_in[10];
  const float* bv       = (const float*)d_in[11];
  const float* We       = (const float*)d_in[12];
  const float* be       = (const float*)d_in[13];
  const float* Wsk      = (const float*)d_in[14];
  const float* bsk      = (const float*)d_in[15];
  const float* Wb       = (const float*)d_in[16];
  const float* Wg1      = (const float*)d_in[17];
  const float* bg1      = (const float*)d_in[18];
  const float* Wg2      = (const float*)d_in[19];
  const float* bg2      = (const float*)d_in[20];
  const float* Wh1      = (const float*)d_in[21];
  const float* bh1      = (const float*)d_in[22];
  const float* Wh2      = (const float*)d_in[23];
  const float* bh2      = (const float*)d_in[24];

  const int N = in_sizes[0] / 5;
  const int E = in_sizes[1] / 2;
  float* out = (float*)d_out;

  char* w = (char*)d_ws;
  auto alloc = [&](size_t bytes)->char*{ char* p = w; w += (bytes + 255) & ~(size_t)255; return p; };
  float* xc     = (float*)alloc((size_t)N*JKW*4);
  float* qkvr   = (float*)alloc((size_t)N*640*4);
  float* attout = (float*)alloc((size_t)N*HIDW*4);     // gate-GEMM tmp
  unsigned short* Bth  = (unsigned short*)alloc((size_t)640*160*2);
  unsigned short* Btl  = (unsigned short*)alloc((size_t)640*160*2);
  unsigned short* Btgh = (unsigned short*)alloc((size_t)160*320*2);
  unsigned short* Btgl = (unsigned short*)alloc((size_t)160*320*2);
  float* bpack  = (float*)alloc(640*4);
  int*   deg    = (int*)alloc((size_t)N*4);
  int*   starts = (int*)alloc((size_t)(N+1)*4);
  int*   cursor = (int*)alloc((size_t)(N+1)*4);
  int*   esrc   = (int*)alloc((size_t)E*4);
  float4* eattr = (float4*)alloc((size_t)E*16);
  const int NB  = (N + 255)/256;
  int*   bsum   = (int*)alloc((size_t)NB*4);
  int*   boff   = (int*)alloc(256*4);
  float* gate   = (float*)alloc((size_t)N*4);
  float* attg   = (float*)alloc((size_t)N*4);
  int*   gs     = (int*)alloc((NGRAPH+1)*4);
  float* gmax   = (float*)alloc(NGRAPH*4);
  float* gden   = (float*)alloc(NGRAPH*4);
  float* pooled = (float*)alloc(NGRAPH*JKW*4);

  const int* srcI = eidx;
  const int* dstI = eidx + E;

  hipMemsetAsync(deg, 0, (size_t)N*4, stream);
  hipMemsetAsync(pooled, 0, (size_t)NGRAPH*JKW*4, stream);

  const int eb = (E + 255)/256;
  k_count<<<eb, 256, 0, stream>>>(dstI, E, deg);
  k_scan1<<<NB, 256, 0, stream>>>(deg, N, starts, bsum);
  k_scan2<<<1, 256, 0, stream>>>(bsum, NB, boff);
  k_scan3<<<NB, 256, 0, stream>>>(starts, cursor, boff, N, E);
  k_fill<<<eb, 256, 0, stream>>>(dstI, srcI, edge_attr, E, cursor, esrc, eattr);

  k_lin_in<<<(N*HIDW + 255)/256, 256, 0, stream>>>(x, W_in, b_in, xc, N);
  k_wpack_gate<<<200, 256, 0, stream>>>(Wg1, Btgh, Btgl);

  const int MB = (N + 63)/64;
  for (int l = 0; l < 2; ++l){
    k_wpack<<<400, 256, 0, stream>>>(Wq + l*25600, Wk + l*25600, Wv + l*25600, Wsk + l*25600,
                                     bq + l*160, bk + l*160, bv + l*160, bsk + l*160, Bth, Btl, bpack);
    dim3 g1(MB, 5);   // NSUB=8 -> 128 cols per wave-col-block, 640/128 = 5
    k_mgemm<8,0><<<g1, 256, 0, stream>>>(xc, JKW, Bth, Btl, bpack, qkvr, 640, N, HIDW);
    k_attn<<<(N + 3)/4, 256, 0, stream>>>(qkvr, eattr, esrc, starts,
                                          We + l*640, be + l*160, Wb + l*480, xc, l*HIDW, N);
  }

  // gate MLP: tmp = relu(xc@Wg1+bg1); gate[n] = tmp.Wg2 + bg2
  dim3 g2(MB, 2);     // NSUB=5 -> 80 cols per wave-col-block, 160/80 = 2
  k_mgemm<5,1><<<g2, 256, 0, stream>>>(xc, JKW, Btgh, Btgl, bg1, attout, HIDW, N, JKW);
  k_gate<<<(N + 3)/4, 256, 0, stream>>>(attout, Wg2, bg2, gate, N);

  k_gbound<<<(N + 255)/256, 256, 0, stream>>>(batch, N, gs);
  k_gstat<<<NGRAPH, 256, 0, stream>>>(gate, gs, gmax, gden);
  k_att<<<(N + 255)/256, 256, 0, stream>>>(gate, batch, gmax, gden, attg, N);
  dim3 g3(NGRAPH, 8);
  k_pool<<<g3, 320, 0, stream>>>(xc, attg, gs, pooled);
  k_head<<<NGRAPH, 320, 0, stream>>>(pooled, Wh1, bh1, Wh2, bh2, out);
}

// Round 4
// 805.223 us; speedup vs baseline: 1.2782x; 1.1764x over previous
//
#include <hip/hip_runtime.h>
#include <math.h>
#include <stddef.h>

#define NHEAD 4
#define DHEAD 40
#define HIDW 160
#define JKW 320
#define NGRAPH 32

typedef __attribute__((ext_vector_type(8))) short short8;
typedef __attribute__((ext_vector_type(4))) float f32x4;

__device__ inline unsigned short f2bf(float x){
  unsigned u = __float_as_uint(x);
  u += 0x7fff + ((u >> 16) & 1);
  return (unsigned short)(u >> 16);
}
__device__ inline float bf2f(unsigned short h){
  return __uint_as_float(((unsigned)h) << 16);
}

// ---------------- CSR build ----------------
__global__ __launch_bounds__(256) void k_count(const int* __restrict__ dst, int E, int* __restrict__ deg){
  int e = blockIdx.x*256 + threadIdx.x;
  if (e < E) atomicAdd(&deg[dst[e]], 1);
}

__global__ __launch_bounds__(256) void k_scan1(const int* __restrict__ deg, int N, int* __restrict__ excl, int* __restrict__ bsum){
  __shared__ int s[256];
  int tid = threadIdx.x;
  int i = blockIdx.x*256 + tid;
  int v = (i < N) ? deg[i] : 0;
  s[tid] = v; __syncthreads();
  for (int off = 1; off < 256; off <<= 1){
    int t = (tid >= off) ? s[tid-off] : 0; __syncthreads();
    s[tid] += t; __syncthreads();
  }
  if (i < N) excl[i] = s[tid] - v;
  if (tid == 255) bsum[blockIdx.x] = s[255];
}

__global__ __launch_bounds__(256) void k_scan2(const int* __restrict__ bsum, int NB, int* __restrict__ boff){
  __shared__ int s[256];
  int tid = threadIdx.x;
  int v = (tid < NB) ? bsum[tid] : 0;
  s[tid] = v; __syncthreads();
  for (int off = 1; off < 256; off <<= 1){
    int t = (tid >= off) ? s[tid-off] : 0; __syncthreads();
    s[tid] += t; __syncthreads();
  }
  boff[tid] = s[tid] - v;
}

__global__ __launch_bounds__(256) void k_scan3(int* __restrict__ starts, int* __restrict__ cursor,
                                               const int* __restrict__ boff, int N, int E){
  int i = blockIdx.x*256 + threadIdx.x;
  if (i < N){
    int v = starts[i] + boff[blockIdx.x];
    starts[i] = v; cursor[i] = v;
  }
  if (i == 0) starts[N] = E;
}

__global__ __launch_bounds__(256) void k_fill(const int* __restrict__ dst, const int* __restrict__ src,
                                              const float* __restrict__ edge_attr, int E,
                                              int* __restrict__ cursor, int* __restrict__ esrc,
                                              float4* __restrict__ eattr){
  int e = blockIdx.x*256 + threadIdx.x;
  if (e < E){
    int d = dst[e];
    int p = atomicAdd(&cursor[d], 1);
    esrc[p] = src[e];
    eattr[p] = *(const float4*)(edge_attr + (size_t)e*4);
  }
}

// ---------------- input linear ----------------
__global__ __launch_bounds__(256) void k_lin_in(const float* __restrict__ x, const float* __restrict__ W,
                                                const float* __restrict__ b, float* __restrict__ xc, int N){
  int idx = blockIdx.x*256 + threadIdx.x;
  if (idx >= N*HIDW) return;
  int n = idx / HIDW, j = idx % HIDW;
  const float* xr = x + n*5;
  float v = b[j];
  #pragma unroll
  for (int c = 0; c < 5; ++c) v += xr[c] * W[c*HIDW + j];
  xc[(size_t)n*JKW + j] = v;
}

// ---------------- weight pack ----------------
__global__ __launch_bounds__(256) void k_wpack(const float* __restrict__ Wq, const float* __restrict__ Wk,
                                               const float* __restrict__ Wv, const float* __restrict__ Ws,
                                               const float* __restrict__ bq, const float* __restrict__ bk,
                                               const float* __restrict__ bv, const float* __restrict__ bs,
                                               unsigned short* __restrict__ Bth, unsigned short* __restrict__ Btl,
                                               float* __restrict__ bp){
  int idx = blockIdx.x*256 + threadIdx.x;
  if (idx < 640*160){
    int j = idx / 160, i = idx % 160;
    int sel = j / HIDW, jj = j % HIDW;
    const float* W = (sel==0) ? Wq : (sel==1) ? Wk : (sel==2) ? Wv : Ws;
    float v = W[i*HIDW + jj];
    unsigned short h = f2bf(v);
    Bth[(size_t)j*160 + i] = h;
    Btl[(size_t)j*160 + i] = f2bf(v - bf2f(h));
  }
  if (idx < 640){
    int sel = idx / HIDW, jj = idx % HIDW;
    const float* bb = (sel==0) ? bq : (sel==1) ? bk : (sel==2) ? bv : bs;
    bp[idx] = bb[jj];
  }
}

__global__ __launch_bounds__(256) void k_wpack_gate(const float* __restrict__ Wg1,
                                                    unsigned short* __restrict__ Bth, unsigned short* __restrict__ Btl){
  int idx = blockIdx.x*256 + threadIdx.x;
  if (idx >= 160*320) return;
  int j = idx / 320, i = idx % 320;
  float v = Wg1[(size_t)i*160 + j];
  unsigned short h = f2bf(v);
  Bth[(size_t)j*320 + i] = h;
  Btl[(size_t)j*320 + i] = f2bf(v - bf2f(h));
}

// ---------------- split-bf16 MFMA GEMM, LDS-staged B ----------------
// C = A[M,K](fp32) @ B, B transposed+split bf16 Bt[col][K].
// block: 64 rows x (16*NSUB) cols, 4 waves stacked in M; B panel staged in LDS per k-step.
// REMAP=1: cols 0..159 -> qr[row][col]; 480..639 -> qr[row][160+cc];
//          cols 160..479 (k,v) -> kv[row][h*80+t*20+(v?10:0)+j]  (h=cc/40,t=(cc%40)/10,j=cc%10)
#define BSTR 40   // LDS col stride in shorts (padded: only free 2-way conflicts)
template<int NSUB, int RELU, int REMAP>
__global__ __launch_bounds__(256) void k_mgemm(const float* __restrict__ A, int lda,
                                               const unsigned short* __restrict__ Bh,
                                               const unsigned short* __restrict__ Bl,
                                               const float* __restrict__ bias,
                                               float* __restrict__ C, int ldc,
                                               float* __restrict__ kv,
                                               int M, int K){
  __shared__ short sBh[16*NSUB*BSTR];
  __shared__ short sBl[16*NSUB*BSTR];
  int tid = threadIdx.x;
  int wv = tid >> 6, lane = tid & 63;
  int quad = lane >> 4, l16 = lane & 15;
  int m0 = blockIdx.x*64 + wv*16;
  int col0 = blockIdx.y * (16*NSUB);
  int arow = m0 + l16; if (arow >= M) arow = M - 1;
  const float* Ap = A + (size_t)arow*lda + quad*8;

  f32x4 acc[NSUB];
  #pragma unroll
  for (int s = 0; s < NSUB; ++s) acc[s] = (f32x4){0.f,0.f,0.f,0.f};

  for (int k0 = 0; k0 < K; k0 += 32){
    // stage B panel: 16*NSUB cols x 32 k shorts, hi+lo
    for (int u = tid; u < 16*NSUB*4; u += 256){
      int col = u >> 2, q4 = u & 3;
      size_t gof = (size_t)(col0 + col)*K + k0 + q4*8;
      *(short8*)(&sBh[col*BSTR + q4*8]) = *(const short8*)(Bh + gof);
      *(short8*)(&sBl[col*BSTR + q4*8]) = *(const short8*)(Bl + gof);
    }
    // A fragment: 8 fp32 -> split bf16
    float4 a0 = *(const float4*)(Ap + k0);
    float4 a1 = *(const float4*)(Ap + k0 + 4);
    float av[8] = {a0.x,a0.y,a0.z,a0.w,a1.x,a1.y,a1.z,a1.w};
    short8 ah, al;
    #pragma unroll
    for (int j = 0; j < 8; ++j){
      unsigned short h = f2bf(av[j]);
      ah[j] = (short)h;
      al[j] = (short)f2bf(av[j] - bf2f(h));
    }
    __syncthreads();
    #pragma unroll
    for (int s = 0; s < NSUB; ++s){
      int lof = (s*16 + l16)*BSTR + quad*8;
      short8 bh = *(const short8*)(&sBh[lof]);
      short8 bl = *(const short8*)(&sBl[lof]);
      acc[s] = __builtin_amdgcn_mfma_f32_16x16x32_bf16(ah, bh, acc[s], 0, 0, 0);
      acc[s] = __builtin_amdgcn_mfma_f32_16x16x32_bf16(al, bh, acc[s], 0, 0, 0);
      acc[s] = __builtin_amdgcn_mfma_f32_16x16x32_bf16(ah, bl, acc[s], 0, 0, 0);
    }
    __syncthreads();
  }
  // C/D layout: col = lane&15, row = quad*4 + reg
  #pragma unroll
  for (int s = 0; s < NSUB; ++s){
    int col = col0 + s*16 + l16;
    float bv = bias ? bias[col] : 0.f;
    #pragma unroll
    for (int r = 0; r < 4; ++r){
      int row = m0 + quad*4 + r;
      if (row >= M) continue;
      float v = acc[s][r] + bv;
      if (RELU) v = fmaxf(v, 0.f);
      if (REMAP){
        int sel = col / 160, cc = col % 160;
        if (sel == 0)      C[(size_t)row*320 + cc] = v;            // q
        else if (sel == 3) C[(size_t)row*320 + 160 + cc] = v;      // r
        else {
          int h = cc/40, rem = cc%40, t = rem/10, j = rem%10;
          kv[(size_t)row*320 + h*80 + t*20 + (sel==2?10:0) + j] = v;
        }
      } else {
        C[(size_t)row*ldc + col] = v;
      }
    }
  }
}

// ---------------- fused edge attention + beta gate ----------------
// wave = 4 edge-slots x (4 heads x 4 quarter-lanes); lane covers 10 dims.
// kv[n] packed per (h,t): 10 k-floats + 10 v-floats = 80B aligned run per lane.
__global__ __launch_bounds__(256) void k_attn(const float* __restrict__ qr,
                                              const float* __restrict__ kv,
                                              const float4* __restrict__ eattr,
                                              const int* __restrict__ esrc,
                                              const int* __restrict__ starts,
                                              const float* __restrict__ We, const float* __restrict__ be,
                                              const float* __restrict__ Wb,
                                              float* __restrict__ xc, int loff, int N){
  int n = blockIdx.x*4 + (threadIdx.x >> 6);
  if (n >= N) return;
  int lane = threadIdx.x & 63;
  int g4 = lane >> 4;
  int w  = lane & 15;
  int hh = w & 3, t = w >> 2;
  int cbase = DHEAD*hh + 10*t;
  int kvbase = (4*hh + t)*20;
  const float scale = 0.15811388300841898f;  // 1/sqrt(40)

  float qs[10];
  const float* qp = qr + (size_t)n*320 + cbase;
  #pragma unroll
  for (int j = 0; j < 10; ++j) qs[j] = qp[j] * scale;

  float qw0=0.f,qw1=0.f,qw2=0.f,qw3=0.f,qb=0.f;
  #pragma unroll
  for (int j = 0; j < 10; ++j){
    int c = cbase + j;
    qw0 += qs[j]*We[c];     qw1 += qs[j]*We[160+c];
    qw2 += qs[j]*We[320+c]; qw3 += qs[j]*We[480+c];
    qb  += qs[j]*be[c];
  }
  qw0 += __shfl_xor(qw0,4); qw0 += __shfl_xor(qw0,8);
  qw1 += __shfl_xor(qw1,4); qw1 += __shfl_xor(qw1,8);
  qw2 += __shfl_xor(qw2,4); qw2 += __shfl_xor(qw2,8);
  qw3 += __shfl_xor(qw3,4); qw3 += __shfl_xor(qw3,8);
  qb  += __shfl_xor(qb ,4); qb  += __shfl_xor(qb ,8);

  float m = -INFINITY, ssum = 0.f;
  float acc[10];
  #pragma unroll
  for (int j = 0; j < 10; ++j) acc[j] = 0.f;
  float sa0=0.f, sa1=0.f, sa2=0.f, sa3=0.f;

  int st = starts[n], en = starts[n+1];
  int epos = st + g4;
  bool valid = (epos < en);
  int sn = 0; float4 ea = make_float4(0.f,0.f,0.f,0.f);
  if (valid){ sn = esrc[epos]; ea = eattr[epos]; }
  float4 kv0, kv1, kv2, kv3, kv4;
  if (valid){
    const float* kp = kv + (size_t)sn*320 + kvbase;
    kv0 = *(const float4*)(kp);   kv1 = *(const float4*)(kp+4);
    kv2 = *(const float4*)(kp+8); kv3 = *(const float4*)(kp+12);
    kv4 = *(const float4*)(kp+16);
  }

  for (int base = st; base < en; base += 4){
    bool cvalid = valid;
    float4 cea = ea;
    float ck[10], cv[10];
    ck[0]=kv0.x; ck[1]=kv0.y; ck[2]=kv0.z; ck[3]=kv0.w;
    ck[4]=kv1.x; ck[5]=kv1.y; ck[6]=kv1.z; ck[7]=kv1.w;
    ck[8]=kv2.x; ck[9]=kv2.y;
    cv[0]=kv2.z; cv[1]=kv2.w;
    cv[2]=kv3.x; cv[3]=kv3.y; cv[4]=kv3.z; cv[5]=kv3.w;
    cv[6]=kv4.x; cv[7]=kv4.y; cv[8]=kv4.z; cv[9]=kv4.w;

    // prefetch next batch
    int np = base + 4 + g4;
    valid = (np < en);
    if (valid){ sn = esrc[np]; ea = eattr[np]; }
    if (valid){
      const float* kp = kv + (size_t)sn*320 + kvbase;
      kv0 = *(const float4*)(kp);   kv1 = *(const float4*)(kp+4);
      kv2 = *(const float4*)(kp+8); kv3 = *(const float4*)(kp+12);
      kv4 = *(const float4*)(kp+16);
    }

    float p = 0.f;
    if (cvalid){
      #pragma unroll
      for (int j = 0; j < 10; ++j) p += qs[j]*ck[j];
    }
    p += __shfl_xor(p, 4);
    p += __shfl_xor(p, 8);
    p += qb + cea.x*qw0 + cea.y*qw1 + cea.z*qw2 + cea.w*qw3;

    if (cvalid){
      float mnew = fmaxf(m, p);
      float fac = expf(m - mnew);
      float ex  = expf(p - mnew);
      ssum = ssum*fac + ex;
      #pragma unroll
      for (int j = 0; j < 10; ++j) acc[j] = acc[j]*fac + ex*cv[j];
      sa0 = sa0*fac + ex*cea.x; sa1 = sa1*fac + ex*cea.y;
      sa2 = sa2*fac + ex*cea.z; sa3 = sa3*fac + ex*cea.w;
      m = mnew;
    }
  }

  #pragma unroll
  for (int xm = 16; xm < 64; xm <<= 1){
    float mo = __shfl_xor(m, xm);
    float so = __shfl_xor(ssum, xm);
    float ao[10];
    #pragma unroll
    for (int j = 0; j < 10; ++j) ao[j] = __shfl_xor(acc[j], xm);
    float t0 = __shfl_xor(sa0, xm), t1 = __shfl_xor(sa1, xm);
    float t2 = __shfl_xor(sa2, xm), t3 = __shfl_xor(sa3, xm);
    float M2 = fmaxf(m, mo);
    float f1 = (m  == -INFINITY) ? 0.f : expf(m  - M2);
    float f2 = (mo == -INFINITY) ? 0.f : expf(mo - M2);
    ssum = ssum*f1 + so*f2;
    #pragma unroll
    for (int j = 0; j < 10; ++j) acc[j] = acc[j]*f1 + ao[j]*f2;
    sa0 = sa0*f1 + t0*f2; sa1 = sa1*f1 + t1*f2;
    sa2 = sa2*f1 + t2*f2; sa3 = sa3*f1 + t3*f2;
    m = M2;
  }

  float inv = (ssum > 0.f) ? 1.f/ssum : 0.f;
  float w0 = sa0*inv, w1 = sa1*inv, w2 = sa2*inv, w3 = sa3*inv;
  float bterm = (ssum > 0.f) ? 1.f : 0.f;
  float outv[10], rr[10];
  const float* rp = qr + (size_t)n*320 + 160 + cbase;
  #pragma unroll
  for (int j = 0; j < 10; ++j){
    int c = cbase + j;
    outv[j] = acc[j]*inv + w0*We[c] + w1*We[160+c] + w2*We[320+c] + w3*We[480+c] + bterm*be[c];
    rr[j] = rp[j];
  }
  float part = 0.f;
  if (g4 == 0){
    #pragma unroll
    for (int j = 0; j < 10; ++j){
      int c = cbase + j;
      part += outv[j]*Wb[c] + rr[j]*Wb[160+c] + (outv[j]-rr[j])*Wb[320+c];
    }
  }
  #pragma unroll
  for (int xm = 1; xm < 64; xm <<= 1) part += __shfl_xor(part, xm);
  float beta = 1.f/(1.f + expf(-part));
  if (g4 == 0){
    float* dp = xc + (size_t)n*JKW + loff + cbase;
    #pragma unroll
    for (int j = 0; j < 10; ++j) dp[j] = beta*rr[j] + (1.f-beta)*outv[j];
  }
}

// ---------------- gate scalar ----------------
__global__ __launch_bounds__(256) void k_gate(const float* __restrict__ tmp, const float* __restrict__ Wg2,
                                              const float* __restrict__ bg2, float* __restrict__ gate, int N){
  int n = blockIdx.x*4 + (threadIdx.x >> 6);
  if (n >= N) return;
  int lane = threadIdx.x & 63;
  float p = tmp[(size_t)n*160 + lane]*Wg2[lane] + tmp[(size_t)n*160 + 64 + lane]*Wg2[64+lane];
  if (lane < 32) p += tmp[(size_t)n*160 + 128 + lane]*Wg2[128+lane];
  #pragma unroll
  for (int xm = 1; xm < 64; xm <<= 1) p += __shfl_xor(p, xm);
  if (lane == 0) gate[n] = p + bg2[0];
}

// ---------------- graph boundaries / pooling ----------------
__global__ __launch_bounds__(256) void k_gbound(const int* __restrict__ batch, int N, int* __restrict__ gs){
  int i = blockIdx.x*256 + threadIdx.x;
  if (i >= N) return;
  int g = batch[i];
  int prev = (i == 0) ? -1 : batch[i-1];
  for (int gg = prev+1; gg <= g; ++gg) gs[gg] = i;
  if (i == N-1){ for (int gg = g+1; gg <= NGRAPH; ++gg) gs[gg] = N; }
}

__global__ __launch_bounds__(256) void k_gstat(const float* __restrict__ gate, const int* __restrict__ gs,
                                               float* __restrict__ gmax, float* __restrict__ gden){
  __shared__ float sm[256];
  int g = blockIdx.x, tid = threadIdx.x;
  int lo = gs[g], hi = gs[g+1];
  float m = -INFINITY;
  for (int i = lo + tid; i < hi; i += 256) m = fmaxf(m, gate[i]);
  sm[tid] = m; __syncthreads();
  for (int off = 128; off; off >>= 1){ if (tid < off) sm[tid] = fmaxf(sm[tid], sm[tid+off]); __syncthreads(); }
  float M = sm[0]; __syncthreads();
  float s = 0.f;
  for (int i = lo + tid; i < hi; i += 256) s += expf(gate[i] - M);
  sm[tid] = s; __syncthreads();
  for (int off = 128; off; off >>= 1){ if (tid < off) sm[tid] += sm[tid+off]; __syncthreads(); }
  if (tid == 0){ gmax[g] = M; gden[g] = sm[0]; }
}

__global__ __launch_bounds__(256) void k_att(const float* __restrict__ gate, const int* __restrict__ batch,
                                             const float* __restrict__ gmax, const float* __restrict__ gden,
                                             float* __restrict__ att, int N){
  int i = blockIdx.x*256 + threadIdx.x;
  if (i >= N) return;
  int g = batch[i];
  float d = gden[g];
  att[i] = (d > 0.f) ? expf(gate[i] - gmax[g])/d : 0.f;
}

__global__ __launch_bounds__(320) void k_pool(const float* __restrict__ xc, const float* __restrict__ att,
                                              const int* __restrict__ gs, float* __restrict__ pooled){
  int g = blockIdx.x, part = blockIdx.y, j = threadIdx.x;
  int lo = gs[g], hi = gs[g+1];
  int len = hi - lo;
  if (len <= 0) return;
  int chunk = (len + (int)gridDim.y - 1) / (int)gridDim.y;
  int a = lo + part*chunk;
  int bnd = a + chunk; if (bnd > hi) bnd = hi;
  if (a >= bnd) return;
  float s = 0.f;
  for (int n = a; n < bnd; ++n) s += att[n]*xc[(size_t)n*JKW + j];
  atomicAdd(&pooled[g*JKW + j], s);
}

__global__ __launch_bounds__(320) void k_head(const float* __restrict__ pooled, const float* __restrict__ Wh1,
                                              const float* __restrict__ bh1, const float* __restrict__ Wh2,
                                              const float* __restrict__ bh2, float* __restrict__ out){
  __shared__ float p[320];
  __shared__ float t[320];
  int g = blockIdx.x, tid = threadIdx.x;
  p[tid] = pooled[g*JKW + tid]; __syncthreads();
  float a = bh1[tid];
  for (int i = 0; i < 320; ++i) a += p[i]*Wh1[i*JKW + tid];
  t[tid] = fmaxf(a, 0.f); __syncthreads();
  if (tid < 6){
    float o = bh2[tid];
    for (int j = 0; j < 320; ++j) o += t[j]*Wh2[j*6 + tid];
    out[g*6 + tid] = o;
  }
}

extern "C" void kernel_launch(void* const* d_in, const int* in_sizes, int n_in,
                              void* d_out, int out_size, void* d_ws, size_t ws_size,
                              hipStream_t stream){
  (void)n_in; (void)out_size; (void)ws_size;
  const float* x        = (const float*)d_in[0];
  const int*   eidx     = (const int*)d_in[1];
  const float* edge_attr= (const float*)d_in[2];
  const int*   batch    = (const int*)d_in[3];
  const float* W_in     = (const float*)d_in[4];
  const float* b_in     = (const float*)d_in[5];
  const float* Wq       = (const float*)d_in[6];
  const float* bq       = (const float*)d_in[7];
  const float* Wk       = (const float*)d_in[8];
  const float* bk       = (const float*)d_in[9];
  const float* Wv       = (const float*)d_in[10];
  const float* bv       = (const float*)d_in[11];
  const float* We       = (const float*)d_in[12];
  const float* be       = (const float*)d_in[13];
  const float* Wsk      = (const float*)d_in[14];
  const float* bsk      = (const float*)d_in[15];
  const float* Wb       = (const float*)d_in[16];
  const float* Wg1      = (const float*)d_in[17];
  const float* bg1      = (const float*)d_in[18];
  const float* Wg2      = (const float*)d_in[19];
  const float* bg2      = (const float*)d_in[20];
  const float* Wh1      = (const float*)d_in[21];
  const float* bh1      = (const float*)d_in[22];
  const float* Wh2      = (const float*)d_in[23];
  const float* bh2      = (const float*)d_in[24];

  const int N = in_sizes[0] / 5;
  const int E = in_sizes[1] / 2;
  float* out = (float*)d_out;

  char* w = (char*)d_ws;
  auto alloc = [&](size_t bytes)->char*{ char* p = w; w += (bytes + 255) & ~(size_t)255; return p; };
  float* xc     = (float*)alloc((size_t)N*JKW*4);
  float* qr     = (float*)alloc((size_t)N*320*4);      // q | skip(r)
  float* kv     = (float*)alloc((size_t)N*320*4);      // packed (h,t): 10k+10v
  float* attout = (float*)alloc((size_t)N*HIDW*4);     // gate-GEMM tmp
  unsigned short* Bth  = (unsigned short*)alloc((size_t)640*160*2);
  unsigned short* Btl  = (unsigned short*)alloc((size_t)640*160*2);
  unsigned short* Btgh = (unsigned short*)alloc((size_t)160*320*2);
  unsigned short* Btgl = (unsigned short*)alloc((size_t)160*320*2);
  float* bpack  = (float*)alloc(640*4);
  int*   deg    = (int*)alloc((size_t)N*4);
  int*   starts = (int*)alloc((size_t)(N+1)*4);
  int*   cursor = (int*)alloc((size_t)(N+1)*4);
  int*   esrc   = (int*)alloc((size_t)E*4);
  float4* eattr = (float4*)alloc((size_t)E*16);
  const int NB  = (N + 255)/256;
  int*   bsum   = (int*)alloc((size_t)NB*4);
  int*   boff   = (int*)alloc(256*4);
  float* gate   = (float*)alloc((size_t)N*4);
  float* attg   = (float*)alloc((size_t)N*4);
  int*   gs     = (int*)alloc((NGRAPH+1)*4);
  float* gmax   = (float*)alloc(NGRAPH*4);
  float* gden   = (float*)alloc(NGRAPH*4);
  float* pooled = (float*)alloc(NGRAPH*JKW*4);

  const int* srcI = eidx;
  const int* dstI = eidx + E;

  hipMemsetAsync(deg, 0, (size_t)N*4, stream);
  hipMemsetAsync(pooled, 0, (size_t)NGRAPH*JKW*4, stream);

  const int eb = (E + 255)/256;
  k_count<<<eb, 256, 0, stream>>>(dstI, E, deg);
  k_scan1<<<NB, 256, 0, stream>>>(deg, N, starts, bsum);
  k_scan2<<<1, 256, 0, stream>>>(bsum, NB, boff);
  k_scan3<<<NB, 256, 0, stream>>>(starts, cursor, boff, N, E);
  k_fill<<<eb, 256, 0, stream>>>(dstI, srcI, edge_attr, E, cursor, esrc, eattr);

  k_lin_in<<<(N*HIDW + 255)/256, 256, 0, stream>>>(x, W_in, b_in, xc, N);
  k_wpack_gate<<<200, 256, 0, stream>>>(Wg1, Btgh, Btgl);

  const int MB = (N + 63)/64;
  for (int l = 0; l < 2; ++l){
    k_wpack<<<400, 256, 0, stream>>>(Wq + l*25600, Wk + l*25600, Wv + l*25600, Wsk + l*25600,
                                     bq + l*160, bk + l*160, bv + l*160, bsk + l*160, Bth, Btl, bpack);
    dim3 g1(MB, 5);   // 128 cols per block, 640/128 = 5
    k_mgemm<8,0,1><<<g1, 256, 0, stream>>>(xc, JKW, Bth, Btl, bpack, qr, 320, kv, N, HIDW);
    k_attn<<<(N + 3)/4, 256, 0, stream>>>(qr, kv, eattr, esrc, starts,
                                          We + l*640, be + l*160, Wb + l*480, xc, l*HIDW, N);
  }

  dim3 g2(MB, 2);     // 80 cols per block, 160/80 = 2
  k_mgemm<5,1,0><<<g2, 256, 0, stream>>>(xc, JKW, Btgh, Btgl, bg1, attout, HIDW, nullptr, N, JKW);
  k_gate<<<(N + 3)/4, 256, 0, stream>>>(attout, Wg2, bg2, gate, N);

  k_gbound<<<(N + 255)/256, 256, 0, stream>>>(batch, N, gs);
  k_gstat<<<NGRAPH, 256, 0, stream>>>(gate, gs, gmax, gden);
  k_att<<<(N + 255)/256, 256, 0, stream>>>(gate, batch, gmax, gden, attg, N);
  dim3 g3(NGRAPH, 8);
  k_pool<<<g3, 320, 0, stream>>>(xc, attg, gs, pooled);
  k_head<<<NGRAPH, 320, 0, stream>>>(pooled, Wh1, bh1, Wh2, bh2, out);
}

// Round 5
// 759.367 us; speedup vs baseline: 1.3553x; 1.0604x over previous
//
#include <hip/hip_runtime.h>
#include <math.h>
#include <stddef.h>

#define NHEAD 4
#define DHEAD 40
#define HIDW 160
#define JKW 320
#define NGRAPH 32

typedef __attribute__((ext_vector_type(8))) short short8;
typedef __attribute__((ext_vector_type(4))) float f32x4;

__device__ inline unsigned short f2bf(float x){
  unsigned u = __float_as_uint(x);
  u += 0x7fff + ((u >> 16) & 1);
  return (unsigned short)(u >> 16);
}
__device__ inline float bf2f(unsigned short h){
  return __uint_as_float(((unsigned)h) << 16);
}

// ---------------- CSR build ----------------
__global__ __launch_bounds__(256) void k_count(const int* __restrict__ dst, int E, int* __restrict__ deg){
  int e = blockIdx.x*256 + threadIdx.x;
  if (e < E) atomicAdd(&deg[dst[e]], 1);
}

__global__ __launch_bounds__(256) void k_scan1(const int* __restrict__ deg, int N, int* __restrict__ excl, int* __restrict__ bsum){
  __shared__ int s[256];
  int tid = threadIdx.x;
  int i = blockIdx.x*256 + tid;
  int v = (i < N) ? deg[i] : 0;
  s[tid] = v; __syncthreads();
  for (int off = 1; off < 256; off <<= 1){
    int t = (tid >= off) ? s[tid-off] : 0; __syncthreads();
    s[tid] += t; __syncthreads();
  }
  if (i < N) excl[i] = s[tid] - v;
  if (tid == 255) bsum[blockIdx.x] = s[255];
}

__global__ __launch_bounds__(256) void k_scan2(const int* __restrict__ bsum, int NB, int* __restrict__ boff){
  __shared__ int s[256];
  int tid = threadIdx.x;
  int v = (tid < NB) ? bsum[tid] : 0;
  s[tid] = v; __syncthreads();
  for (int off = 1; off < 256; off <<= 1){
    int t = (tid >= off) ? s[tid-off] : 0; __syncthreads();
    s[tid] += t; __syncthreads();
  }
  boff[tid] = s[tid] - v;
}

__global__ __launch_bounds__(256) void k_scan3(int* __restrict__ starts, int* __restrict__ cursor,
                                               const int* __restrict__ boff, int N, int E){
  int i = blockIdx.x*256 + threadIdx.x;
  if (i < N){
    int v = starts[i] + boff[blockIdx.x];
    starts[i] = v; cursor[i] = v;
  }
  if (i == 0) starts[N] = E;
}

__global__ __launch_bounds__(256) void k_fill(const int* __restrict__ dst, const int* __restrict__ src,
                                              const float* __restrict__ edge_attr, int E,
                                              int* __restrict__ cursor, int* __restrict__ esrc,
                                              float4* __restrict__ eattr){
  int e = blockIdx.x*256 + threadIdx.x;
  if (e < E){
    int d = dst[e];
    int p = atomicAdd(&cursor[d], 1);
    esrc[p] = src[e];
    eattr[p] = *(const float4*)(edge_attr + (size_t)e*4);
  }
}

// ---------------- input linear ----------------
__global__ __launch_bounds__(256) void k_lin_in(const float* __restrict__ x, const float* __restrict__ W,
                                                const float* __restrict__ b, float* __restrict__ xc, int N){
  int idx = blockIdx.x*256 + threadIdx.x;
  if (idx >= N*HIDW) return;
  int n = idx / HIDW, j = idx % HIDW;
  const float* xr = x + n*5;
  float v = b[j];
  #pragma unroll
  for (int c = 0; c < 5; ++c) v += xr[c] * W[c*HIDW + j];
  xc[(size_t)n*JKW + j] = v;
}

// ---------------- weight pack ----------------
__global__ __launch_bounds__(256) void k_wpack(const float* __restrict__ Wq, const float* __restrict__ Wk,
                                               const float* __restrict__ Wv, const float* __restrict__ Ws,
                                               const float* __restrict__ bq, const float* __restrict__ bk,
                                               const float* __restrict__ bv, const float* __restrict__ bs,
                                               unsigned short* __restrict__ Bth, unsigned short* __restrict__ Btl,
                                               float* __restrict__ bp){
  int idx = blockIdx.x*256 + threadIdx.x;
  if (idx < 640*160){
    int j = idx / 160, i = idx % 160;
    int sel = j / HIDW, jj = j % HIDW;
    const float* W = (sel==0) ? Wq : (sel==1) ? Wk : (sel==2) ? Wv : Ws;
    float v = W[i*HIDW + jj];
    unsigned short h = f2bf(v);
    Bth[(size_t)j*160 + i] = h;
    Btl[(size_t)j*160 + i] = f2bf(v - bf2f(h));
  }
  if (idx < 640){
    int sel = idx / HIDW, jj = idx % HIDW;
    const float* bb = (sel==0) ? bq : (sel==1) ? bk : (sel==2) ? bv : bs;
    bp[idx] = bb[jj];
  }
}

__global__ __launch_bounds__(256) void k_wpack_gate(const float* __restrict__ Wg1,
                                                    unsigned short* __restrict__ Bth, unsigned short* __restrict__ Btl){
  int idx = blockIdx.x*256 + threadIdx.x;
  if (idx >= 160*320) return;
  int j = idx / 320, i = idx % 320;
  float v = Wg1[(size_t)i*160 + j];
  unsigned short h = f2bf(v);
  Bth[(size_t)j*320 + i] = h;
  Btl[(size_t)j*320 + i] = f2bf(v - bf2f(h));
}

// ---------------- split-bf16 MFMA GEMM, LDS-staged B ----------------
// REMAP=1: cols 0..159 -> qr[row][col]; 480..639 -> qr[row][160+cc];
//          cols 160..479 (k,v) -> fp16 kv16[row][ (h*4+t)*24 + (v?10:0) + j ]  (row stride 384 halves)
#define BSTR 40
template<int NSUB, int RELU, int REMAP>
__global__ __launch_bounds__(256) void k_mgemm(const float* __restrict__ A, int lda,
                                               const unsigned short* __restrict__ Bh,
                                               const unsigned short* __restrict__ Bl,
                                               const float* __restrict__ bias,
                                               float* __restrict__ C, int ldc,
                                               _Float16* __restrict__ kv16,
                                               int M, int K){
  __shared__ short sBh[16*NSUB*BSTR];
  __shared__ short sBl[16*NSUB*BSTR];
  int tid = threadIdx.x;
  int wv = tid >> 6, lane = tid & 63;
  int quad = lane >> 4, l16 = lane & 15;
  int m0 = blockIdx.x*64 + wv*16;
  int col0 = blockIdx.y * (16*NSUB);
  int arow = m0 + l16; if (arow >= M) arow = M - 1;
  const float* Ap = A + (size_t)arow*lda + quad*8;

  f32x4 acc[NSUB];
  #pragma unroll
  for (int s = 0; s < NSUB; ++s) acc[s] = (f32x4){0.f,0.f,0.f,0.f};

  for (int k0 = 0; k0 < K; k0 += 32){
    for (int u = tid; u < 16*NSUB*4; u += 256){
      int col = u >> 2, q4 = u & 3;
      size_t gof = (size_t)(col0 + col)*K + k0 + q4*8;
      *(short8*)(&sBh[col*BSTR + q4*8]) = *(const short8*)(Bh + gof);
      *(short8*)(&sBl[col*BSTR + q4*8]) = *(const short8*)(Bl + gof);
    }
    float4 a0 = *(const float4*)(Ap + k0);
    float4 a1 = *(const float4*)(Ap + k0 + 4);
    float av[8] = {a0.x,a0.y,a0.z,a0.w,a1.x,a1.y,a1.z,a1.w};
    short8 ah, al;
    #pragma unroll
    for (int j = 0; j < 8; ++j){
      unsigned short h = f2bf(av[j]);
      ah[j] = (short)h;
      al[j] = (short)f2bf(av[j] - bf2f(h));
    }
    __syncthreads();
    #pragma unroll
    for (int s = 0; s < NSUB; ++s){
      int lof = (s*16 + l16)*BSTR + quad*8;
      short8 bh = *(const short8*)(&sBh[lof]);
      short8 bl = *(const short8*)(&sBl[lof]);
      acc[s] = __builtin_amdgcn_mfma_f32_16x16x32_bf16(ah, bh, acc[s], 0, 0, 0);
      acc[s] = __builtin_amdgcn_mfma_f32_16x16x32_bf16(al, bh, acc[s], 0, 0, 0);
      acc[s] = __builtin_amdgcn_mfma_f32_16x16x32_bf16(ah, bl, acc[s], 0, 0, 0);
    }
    __syncthreads();
  }
  #pragma unroll
  for (int s = 0; s < NSUB; ++s){
    int col = col0 + s*16 + l16;
    float bv = bias ? bias[col] : 0.f;
    #pragma unroll
    for (int r = 0; r < 4; ++r){
      int row = m0 + quad*4 + r;
      if (row >= M) continue;
      float v = acc[s][r] + bv;
      if (RELU) v = fmaxf(v, 0.f);
      if (REMAP){
        int sel = col / 160, cc = col % 160;
        if (sel == 0)      C[(size_t)row*320 + cc] = v;            // q
        else if (sel == 3) C[(size_t)row*320 + 160 + cc] = v;      // r
        else {
          int h = cc/40, rem = cc%40, t = rem/10, j = rem%10;
          kv16[(size_t)row*384 + (size_t)(h*4+t)*24 + (sel==2?10:0) + j] = (_Float16)v;
        }
      } else {
        C[(size_t)row*ldc + col] = v;
      }
    }
  }
}

// ---------------- fused edge attention + beta gate ----------------
// wave = 4 edge-slots x (4 heads x 4 quarter-lanes); slot row = 24 fp16 {k0..9,v0..9,pad4} = 48B aligned
__global__ __launch_bounds__(256) void k_attn(const float* __restrict__ qr,
                                              const _Float16* __restrict__ kv16,
                                              const float4* __restrict__ eattr,
                                              const int* __restrict__ esrc,
                                              const int* __restrict__ starts,
                                              const float* __restrict__ We, const float* __restrict__ be,
                                              const float* __restrict__ Wb,
                                              float* __restrict__ xc, int loff, int N){
  int n = blockIdx.x*4 + (threadIdx.x >> 6);
  if (n >= N) return;
  int lane = threadIdx.x & 63;
  int g4 = lane >> 4;
  int w  = lane & 15;
  int hh = w & 3, t = w >> 2;
  int cbase = DHEAD*hh + 10*t;
  int slot = hh*4 + t;
  const float scale = 0.15811388300841898f;  // 1/sqrt(40)

  float qs[10];
  const float* qp = qr + (size_t)n*320 + cbase;
  #pragma unroll
  for (int j = 0; j < 10; ++j) qs[j] = qp[j] * scale;

  float qw0=0.f,qw1=0.f,qw2=0.f,qw3=0.f,qb=0.f;
  #pragma unroll
  for (int j = 0; j < 10; ++j){
    int c = cbase + j;
    qw0 += qs[j]*We[c];     qw1 += qs[j]*We[160+c];
    qw2 += qs[j]*We[320+c]; qw3 += qs[j]*We[480+c];
    qb  += qs[j]*be[c];
  }
  qw0 += __shfl_xor(qw0,4); qw0 += __shfl_xor(qw0,8);
  qw1 += __shfl_xor(qw1,4); qw1 += __shfl_xor(qw1,8);
  qw2 += __shfl_xor(qw2,4); qw2 += __shfl_xor(qw2,8);
  qw3 += __shfl_xor(qw3,4); qw3 += __shfl_xor(qw3,8);
  qb  += __shfl_xor(qb ,4); qb  += __shfl_xor(qb ,8);

  float m = -INFINITY, ssum = 0.f;
  float acc[10];
  #pragma unroll
  for (int j = 0; j < 10; ++j) acc[j] = 0.f;
  float sa0=0.f, sa1=0.f, sa2=0.f, sa3=0.f;

  int st = starts[n], en = starts[n+1];
  int B = (en - st + 3) >> 2;

  // pipeline: meta 2 deep, kv 1 deep
  int snA = 0, snB = 0; float4 eaA, eaB; bool vA = false, vB = false;
  eaA = make_float4(0.f,0.f,0.f,0.f); eaB = eaA;
  {
    int p0 = st + g4;
    vA = (p0 < en); if (vA){ snA = esrc[p0]; eaA = eattr[p0]; }
    int p1 = st + 4 + g4;
    vB = (p1 < en); if (vB){ snB = esrc[p1]; eaB = eattr[p1]; }
  }
  float4 c0, c1, c2;
  if (vA){
    const float4* kp = (const float4*)(kv16 + (size_t)snA*384 + (size_t)slot*24);
    c0 = kp[0]; c1 = kp[1]; c2 = kp[2];
  }

  for (int b = 0; b < B; ++b){
    // stage C meta (b+2): independent load
    int snC = 0; float4 eaC = make_float4(0.f,0.f,0.f,0.f); bool vC;
    int p2 = st + (b+2)*4 + g4;
    vC = (p2 < en); if (vC){ snC = esrc[p2]; eaC = eattr[p2]; }
    // kv for b+1 (meta loaded one iteration ago)
    float4 n0, n1, n2;
    if (vB){
      const float4* kp = (const float4*)(kv16 + (size_t)snB*384 + (size_t)slot*24);
      n0 = kp[0]; n1 = kp[1]; n2 = kp[2];
    }
    // compute batch b from c0..c2 / eaA / vA
    union U { float4 f4; _Float16 h[8]; };
    U u0, u1, u2; u0.f4 = c0; u1.f4 = c1; u2.f4 = c2;
    float ck[10], cv[10];
    #pragma unroll
    for (int j = 0; j < 8; ++j) ck[j] = (float)u0.h[j];
    ck[8] = (float)u1.h[0]; ck[9] = (float)u1.h[1];
    #pragma unroll
    for (int j = 0; j < 6; ++j) cv[j] = (float)u1.h[2+j];
    #pragma unroll
    for (int j = 0; j < 4; ++j) cv[6+j] = (float)u2.h[j];

    float p = 0.f;
    if (vA){
      #pragma unroll
      for (int j = 0; j < 10; ++j) p += qs[j]*ck[j];
    }
    p += __shfl_xor(p, 4);
    p += __shfl_xor(p, 8);
    p += qb + eaA.x*qw0 + eaA.y*qw1 + eaA.z*qw2 + eaA.w*qw3;

    if (vA){
      float mnew = fmaxf(m, p);
      float fac = expf(m - mnew);
      float ex  = expf(p - mnew);
      ssum = ssum*fac + ex;
      #pragma unroll
      for (int j = 0; j < 10; ++j) acc[j] = acc[j]*fac + ex*cv[j];
      sa0 = sa0*fac + ex*eaA.x; sa1 = sa1*fac + ex*eaA.y;
      sa2 = sa2*fac + ex*eaA.z; sa3 = sa3*fac + ex*eaA.w;
      m = mnew;
    }
    // rotate
    snA = snB; eaA = eaB; vA = vB;
    snB = snC; eaB = eaC; vB = vC;
    c0 = n0; c1 = n1; c2 = n2;
  }

  #pragma unroll
  for (int xm = 16; xm < 64; xm <<= 1){
    float mo = __shfl_xor(m, xm);
    float so = __shfl_xor(ssum, xm);
    float ao[10];
    #pragma unroll
    for (int j = 0; j < 10; ++j) ao[j] = __shfl_xor(acc[j], xm);
    float t0 = __shfl_xor(sa0, xm), t1 = __shfl_xor(sa1, xm);
    float t2 = __shfl_xor(sa2, xm), t3 = __shfl_xor(sa3, xm);
    float M2 = fmaxf(m, mo);
    float f1 = (m  == -INFINITY) ? 0.f : expf(m  - M2);
    float f2 = (mo == -INFINITY) ? 0.f : expf(mo - M2);
    ssum = ssum*f1 + so*f2;
    #pragma unroll
    for (int j = 0; j < 10; ++j) acc[j] = acc[j]*f1 + ao[j]*f2;
    sa0 = sa0*f1 + t0*f2; sa1 = sa1*f1 + t1*f2;
    sa2 = sa2*f1 + t2*f2; sa3 = sa3*f1 + t3*f2;
    m = M2;
  }

  float inv = (ssum > 0.f) ? 1.f/ssum : 0.f;
  float w0 = sa0*inv, w1 = sa1*inv, w2 = sa2*inv, w3 = sa3*inv;
  float bterm = (ssum > 0.f) ? 1.f : 0.f;
  float outv[10], rr[10];
  const float* rp = qr + (size_t)n*320 + 160 + cbase;
  #pragma unroll
  for (int j = 0; j < 10; ++j){
    int c = cbase + j;
    outv[j] = acc[j]*inv + w0*We[c] + w1*We[160+c] + w2*We[320+c] + w3*We[480+c] + bterm*be[c];
    rr[j] = rp[j];
  }
  float part = 0.f;
  if (g4 == 0){
    #pragma unroll
    for (int j = 0; j < 10; ++j){
      int c = cbase + j;
      part += outv[j]*Wb[c] + rr[j]*Wb[160+c] + (outv[j]-rr[j])*Wb[320+c];
    }
  }
  #pragma unroll
  for (int xm = 1; xm < 64; xm <<= 1) part += __shfl_xor(part, xm);
  float beta = 1.f/(1.f + expf(-part));
  if (g4 == 0){
    float* dp = xc + (size_t)n*JKW + loff + cbase;
    #pragma unroll
    for (int j = 0; j < 10; ++j) dp[j] = beta*rr[j] + (1.f-beta)*outv[j];
  }
}

// ---------------- gate scalar ----------------
__global__ __launch_bounds__(256) void k_gate(const float* __restrict__ tmp, const float* __restrict__ Wg2,
                                              const float* __restrict__ bg2, float* __restrict__ gate, int N){
  int n = blockIdx.x*4 + (threadIdx.x >> 6);
  if (n >= N) return;
  int lane = threadIdx.x & 63;
  float p = tmp[(size_t)n*160 + lane]*Wg2[lane] + tmp[(size_t)n*160 + 64 + lane]*Wg2[64+lane];
  if (lane < 32) p += tmp[(size_t)n*160 + 128 + lane]*Wg2[128+lane];
  #pragma unroll
  for (int xm = 1; xm < 64; xm <<= 1) p += __shfl_xor(p, xm);
  if (lane == 0) gate[n] = p + bg2[0];
}

// ---------------- graph boundaries / pooling ----------------
__global__ __launch_bounds__(256) void k_gbound(const int* __restrict__ batch, int N, int* __restrict__ gs){
  int i = blockIdx.x*256 + threadIdx.x;
  if (i >= N) return;
  int g = batch[i];
  int prev = (i == 0) ? -1 : batch[i-1];
  for (int gg = prev+1; gg <= g; ++gg) gs[gg] = i;
  if (i == N-1){ for (int gg = g+1; gg <= NGRAPH; ++gg) gs[gg] = N; }
}

__global__ __launch_bounds__(256) void k_gstat(const float* __restrict__ gate, const int* __restrict__ gs,
                                               float* __restrict__ gmax, float* __restrict__ gden){
  __shared__ float sm[256];
  int g = blockIdx.x, tid = threadIdx.x;
  int lo = gs[g], hi = gs[g+1];
  float m = -INFINITY;
  for (int i = lo + tid; i < hi; i += 256) m = fmaxf(m, gate[i]);
  sm[tid] = m; __syncthreads();
  for (int off = 128; off; off >>= 1){ if (tid < off) sm[tid] = fmaxf(sm[tid], sm[tid+off]); __syncthreads(); }
  float M = sm[0]; __syncthreads();
  float s = 0.f;
  for (int i = lo + tid; i < hi; i += 256) s += expf(gate[i] - M);
  sm[tid] = s; __syncthreads();
  for (int off = 128; off; off >>= 1){ if (tid < off) sm[tid] += sm[tid+off]; __syncthreads(); }
  if (tid == 0){ gmax[g] = M; gden[g] = sm[0]; }
}

__global__ __launch_bounds__(256) void k_att(const float* __restrict__ gate, const int* __restrict__ batch,
                                             const float* __restrict__ gmax, const float* __restrict__ gden,
                                             float* __restrict__ att, int N){
  int i = blockIdx.x*256 + threadIdx.x;
  if (i >= N) return;
  int g = batch[i];
  float d = gden[g];
  att[i] = (d > 0.f) ? expf(gate[i] - gmax[g])/d : 0.f;
}

__global__ __launch_bounds__(320) void k_pool(const float* __restrict__ xc, const float* __restrict__ att,
                                              const int* __restrict__ gs, float* __restrict__ pooled){
  int g = blockIdx.x, part = blockIdx.y, j = threadIdx.x;
  int lo = gs[g], hi = gs[g+1];
  int len = hi - lo;
  if (len <= 0) return;
  int chunk = (len + (int)gridDim.y - 1) / (int)gridDim.y;
  int a = lo + part*chunk;
  int bnd = a + chunk; if (bnd > hi) bnd = hi;
  if (a >= bnd) return;
  float s = 0.f;
  for (int n = a; n < bnd; ++n) s += att[n]*xc[(size_t)n*JKW + j];
  atomicAdd(&pooled[g*JKW + j], s);
}

__global__ __launch_bounds__(320) void k_head(const float* __restrict__ pooled, const float* __restrict__ Wh1,
                                              const float* __restrict__ bh1, const float* __restrict__ Wh2,
                                              const float* __restrict__ bh2, float* __restrict__ out){
  __shared__ float p[320];
  __shared__ float t[320];
  int g = blockIdx.x, tid = threadIdx.x;
  p[tid] = pooled[g*JKW + tid]; __syncthreads();
  float a = bh1[tid];
  for (int i = 0; i < 320; ++i) a += p[i]*Wh1[i*JKW + tid];
  t[tid] = fmaxf(a, 0.f); __syncthreads();
  if (tid < 6){
    float o = bh2[tid];
    for (int j = 0; j < 320; ++j) o += t[j]*Wh2[j*6 + tid];
    out[g*6 + tid] = o;
  }
}

extern "C" void kernel_launch(void* const* d_in, const int* in_sizes, int n_in,
                              void* d_out, int out_size, void* d_ws, size_t ws_size,
                              hipStream_t stream){
  (void)n_in; (void)out_size; (void)ws_size;
  const float* x        = (const float*)d_in[0];
  const int*   eidx     = (const int*)d_in[1];
  const float* edge_attr= (const float*)d_in[2];
  const int*   batch    = (const int*)d_in[3];
  const float* W_in     = (const float*)d_in[4];
  const float* b_in     = (const float*)d_in[5];
  const float* Wq       = (const float*)d_in[6];
  const float* bq       = (const float*)d_in[7];
  const float* Wk       = (const float*)d_in[8];
  const float* bk       = (const float*)d_in[9];
  const float* Wv       = (const float*)d_in[10];
  const float* bv       = (const float*)d_in[11];
  const float* We       = (const float*)d_in[12];
  const float* be       = (const float*)d_in[13];
  const float* Wsk      = (const float*)d_in[14];
  const float* bsk      = (const float*)d_in[15];
  const float* Wb       = (const float*)d_in[16];
  const float* Wg1      = (const float*)d_in[17];
  const float* bg1      = (const float*)d_in[18];
  const float* Wg2      = (const float*)d_in[19];
  const float* bg2      = (const float*)d_in[20];
  const float* Wh1      = (const float*)d_in[21];
  const float* bh1      = (const float*)d_in[22];
  const float* Wh2      = (const float*)d_in[23];
  const float* bh2      = (const float*)d_in[24];

  const int N = in_sizes[0] / 5;
  const int E = in_sizes[1] / 2;
  float* out = (float*)d_out;

  char* w = (char*)d_ws;
  auto alloc = [&](size_t bytes)->char*{ char* p = w; w += (bytes + 255) & ~(size_t)255; return p; };
  float* xc     = (float*)alloc((size_t)N*JKW*4);
  float* qr     = (float*)alloc((size_t)N*320*4);          // q | skip(r), fp32
  _Float16* kv16= (_Float16*)alloc((size_t)N*384*2);       // 16 slots x {k10,v10,pad4} fp16
  float* attout = (float*)alloc((size_t)N*HIDW*4);
  unsigned short* Bth  = (unsigned short*)alloc((size_t)640*160*2);
  unsigned short* Btl  = (unsigned short*)alloc((size_t)640*160*2);
  unsigned short* Btgh = (unsigned short*)alloc((size_t)160*320*2);
  unsigned short* Btgl = (unsigned short*)alloc((size_t)160*320*2);
  float* bpack  = (float*)alloc(640*4);
  int*   deg    = (int*)alloc((size_t)N*4);
  int*   starts = (int*)alloc((size_t)(N+1)*4);
  int*   cursor = (int*)alloc((size_t)(N+1)*4);
  int*   esrc   = (int*)alloc((size_t)E*4);
  float4* eattr = (float4*)alloc((size_t)E*16);
  const int NB  = (N + 255)/256;
  int*   bsum   = (int*)alloc((size_t)NB*4);
  int*   boff   = (int*)alloc(256*4);
  float* gate   = (float*)alloc((size_t)N*4);
  float* attg   = (float*)alloc((size_t)N*4);
  int*   gs     = (int*)alloc((NGRAPH+1)*4);
  float* gmax   = (float*)alloc(NGRAPH*4);
  float* gden   = (float*)alloc(NGRAPH*4);
  float* pooled = (float*)alloc(NGRAPH*JKW*4);

  const int* srcI = eidx;
  const int* dstI = eidx + E;

  hipMemsetAsync(deg, 0, (size_t)N*4, stream);
  hipMemsetAsync(pooled, 0, (size_t)NGRAPH*JKW*4, stream);

  const int eb = (E + 255)/256;
  k_count<<<eb, 256, 0, stream>>>(dstI, E, deg);
  k_scan1<<<NB, 256, 0, stream>>>(deg, N, starts, bsum);
  k_scan2<<<1, 256, 0, stream>>>(bsum, NB, boff);
  k_scan3<<<NB, 256, 0, stream>>>(starts, cursor, boff, N, E);
  k_fill<<<eb, 256, 0, stream>>>(dstI, srcI, edge_attr, E, cursor, esrc, eattr);

  k_lin_in<<<(N*HIDW + 255)/256, 256, 0, stream>>>(x, W_in, b_in, xc, N);
  k_wpack_gate<<<200, 256, 0, stream>>>(Wg1, Btgh, Btgl);

  const int MB = (N + 63)/64;
  for (int l = 0; l < 2; ++l){
    k_wpack<<<400, 256, 0, stream>>>(Wq + l*25600, Wk + l*25600, Wv + l*25600, Wsk + l*25600,
                                     bq + l*160, bk + l*160, bv + l*160, bsk + l*160, Bth, Btl, bpack);
    dim3 g1(MB, 5);
    k_mgemm<8,0,1><<<g1, 256, 0, stream>>>(xc, JKW, Bth, Btl, bpack, qr, 320, kv16, N, HIDW);
    k_attn<<<(N + 3)/4, 256, 0, stream>>>(qr, kv16, eattr, esrc, starts,
                                          We + l*640, be + l*160, Wb + l*480, xc, l*HIDW, N);
  }

  dim3 g2(MB, 2);
  k_mgemm<5,1,0><<<g2, 256, 0, stream>>>(xc, JKW, Btgh, Btgl, bg1, attout, HIDW, nullptr, N, JKW);
  k_gate<<<(N + 3)/4, 256, 0, stream>>>(attout, Wg2, bg2, gate, N);

  k_gbound<<<(N + 255)/256, 256, 0, stream>>>(batch, N, gs);
  k_gstat<<<NGRAPH, 256, 0, stream>>>(gate, gs, gmax, gden);
  k_att<<<(N + 255)/256, 256, 0, stream>>>(gate, batch, gmax, gden, attg, N);
  dim3 g3(NGRAPH, 8);
  k_pool<<<g3, 320, 0, stream>>>(xc, attg, gs, pooled);
  k_head<<<NGRAPH, 320, 0, stream>>>(pooled, Wh1, bh1, Wh2, bh2, out);
}

// Round 6
// 737.909 us; speedup vs baseline: 1.3948x; 1.0291x over previous
//
#include <hip/hip_runtime.h>
#include <math.h>
#include <stddef.h>

#define NHEAD 4
#define DHEAD 40
#define HIDW 160
#define JKW 320
#define NGRAPH 32

typedef __attribute__((ext_vector_type(8))) short short8;
typedef __attribute__((ext_vector_type(4))) float f32x4;

__device__ inline unsigned short f2bf(float x){
  unsigned u = __float_as_uint(x);
  u += 0x7fff + ((u >> 16) & 1);
  return (unsigned short)(u >> 16);
}
__device__ inline float bf2f(unsigned short h){
  return __uint_as_float(((unsigned)h) << 16);
}

// ---------------- CSR build ----------------
__global__ __launch_bounds__(256) void k_count(const int* __restrict__ dst, int E, int* __restrict__ deg){
  int e = blockIdx.x*256 + threadIdx.x;
  if (e < E) atomicAdd(&deg[dst[e]], 1);
}

__global__ __launch_bounds__(256) void k_scan1(const int* __restrict__ deg, int N, int* __restrict__ excl, int* __restrict__ bsum){
  __shared__ int s[256];
  int tid = threadIdx.x;
  int i = blockIdx.x*256 + tid;
  int v = (i < N) ? deg[i] : 0;
  s[tid] = v; __syncthreads();
  for (int off = 1; off < 256; off <<= 1){
    int t = (tid >= off) ? s[tid-off] : 0; __syncthreads();
    s[tid] += t; __syncthreads();
  }
  if (i < N) excl[i] = s[tid] - v;
  if (tid == 255) bsum[blockIdx.x] = s[255];
}

__global__ __launch_bounds__(256) void k_scan2(const int* __restrict__ bsum, int NB, int* __restrict__ boff){
  __shared__ int s[256];
  int tid = threadIdx.x;
  int v = (tid < NB) ? bsum[tid] : 0;
  s[tid] = v; __syncthreads();
  for (int off = 1; off < 256; off <<= 1){
    int t = (tid >= off) ? s[tid-off] : 0; __syncthreads();
    s[tid] += t; __syncthreads();
  }
  boff[tid] = s[tid] - v;
}

__global__ __launch_bounds__(256) void k_scan3(int* __restrict__ starts, int* __restrict__ cursor,
                                               const int* __restrict__ boff, int N, int E){
  int i = blockIdx.x*256 + threadIdx.x;
  if (i < N){
    int v = starts[i] + boff[blockIdx.x];
    starts[i] = v; cursor[i] = v;
  }
  if (i == 0) starts[N] = E;
}

__global__ __launch_bounds__(256) void k_fill(const int* __restrict__ dst, const int* __restrict__ src,
                                              const float* __restrict__ edge_attr, int E,
                                              int* __restrict__ cursor, int* __restrict__ esrc,
                                              float4* __restrict__ eattr){
  int e = blockIdx.x*256 + threadIdx.x;
  if (e < E){
    int d = dst[e];
    int p = atomicAdd(&cursor[d], 1);
    esrc[p] = src[e];
    eattr[p] = *(const float4*)(edge_attr + (size_t)e*4);
  }
}

// ---------------- input linear ----------------
__global__ __launch_bounds__(256) void k_lin_in(const float* __restrict__ x, const float* __restrict__ W,
                                                const float* __restrict__ b, float* __restrict__ xc, int N){
  int idx = blockIdx.x*256 + threadIdx.x;
  if (idx >= N*HIDW) return;
  int n = idx / HIDW, j = idx % HIDW;
  const float* xr = x + n*5;
  float v = b[j];
  #pragma unroll
  for (int c = 0; c < 5; ++c) v += xr[c] * W[c*HIDW + j];
  xc[(size_t)n*JKW + j] = v;
}

// ---------------- weight pack ----------------
__global__ __launch_bounds__(256) void k_wpack(const float* __restrict__ Wq, const float* __restrict__ Wk,
                                               const float* __restrict__ Wv, const float* __restrict__ Ws,
                                               const float* __restrict__ bq, const float* __restrict__ bk,
                                               const float* __restrict__ bv, const float* __restrict__ bs,
                                               unsigned short* __restrict__ Bth, unsigned short* __restrict__ Btl,
                                               float* __restrict__ bp){
  int idx = blockIdx.x*256 + threadIdx.x;
  if (idx < 640*160){
    int j = idx / 160, i = idx % 160;
    int sel = j / HIDW, jj = j % HIDW;
    const float* W = (sel==0) ? Wq : (sel==1) ? Wk : (sel==2) ? Wv : Ws;
    float v = W[i*HIDW + jj];
    unsigned short h = f2bf(v);
    Bth[(size_t)j*160 + i] = h;
    Btl[(size_t)j*160 + i] = f2bf(v - bf2f(h));
  }
  if (idx < 640){
    int sel = idx / HIDW, jj = idx % HIDW;
    const float* bb = (sel==0) ? bq : (sel==1) ? bk : (sel==2) ? bv : bs;
    bp[idx] = bb[jj];
  }
}

__global__ __launch_bounds__(256) void k_wpack_gate(const float* __restrict__ Wg1,
                                                    unsigned short* __restrict__ Bth, unsigned short* __restrict__ Btl){
  int idx = blockIdx.x*256 + threadIdx.x;
  if (idx >= 160*320) return;
  int j = idx / 320, i = idx % 320;
  float v = Wg1[(size_t)i*160 + j];
  unsigned short h = f2bf(v);
  Bth[(size_t)j*320 + i] = h;
  Btl[(size_t)j*320 + i] = f2bf(v - bf2f(h));
}

// ---------------- split-bf16 MFMA GEMM v3: 128-row block, 32 rows/wave ----------------
// MODE 1 (QKV remap): cols 0..159 -> qr[row][col]; 480..639 -> qr[row][160+cc];
//                     160..479 -> fp16 kv16[row][(h*4+t)*24 + (v?10:0)+j], row stride 384
// MODE 2 (gate fuse): v = relu(acc+bg1[col]); atomicAdd(gate[row], sum_col v*Wg2[col])
#define BSTR 40
template<int NSUB, int MODE>
__global__ __launch_bounds__(256) void k_mgemm(const float* __restrict__ A, int lda,
                                               const unsigned short* __restrict__ Bh,
                                               const unsigned short* __restrict__ Bl,
                                               const float* __restrict__ bias,
                                               float* __restrict__ C,
                                               _Float16* __restrict__ kv16,
                                               const float* __restrict__ Wg2,
                                               float* __restrict__ gate,
                                               int M, int K){
  __shared__ short sBh[16*NSUB*BSTR];
  __shared__ short sBl[16*NSUB*BSTR];
  int tid = threadIdx.x;
  int wv = tid >> 6, lane = tid & 63;
  int quad = lane >> 4, l16 = lane & 15;
  int m0 = blockIdx.x*128 + wv*32;
  int col0 = blockIdx.y * (16*NSUB);
  int ar0 = m0 + l16;      if (ar0 >= M) ar0 = M - 1;
  int ar1 = m0 + 16 + l16; if (ar1 >= M) ar1 = M - 1;
  const float* Ap0 = A + (size_t)ar0*lda + quad*8;
  const float* Ap1 = A + (size_t)ar1*lda + quad*8;

  f32x4 acc[2][NSUB];
  #pragma unroll
  for (int g = 0; g < 2; ++g)
    #pragma unroll
    for (int s = 0; s < NSUB; ++s) acc[g][s] = (f32x4){0.f,0.f,0.f,0.f};

  for (int k0 = 0; k0 < K; k0 += 32){
    for (int u = tid; u < 16*NSUB*4; u += 256){
      int col = u >> 2, q4 = u & 3;
      size_t gof = (size_t)(col0 + col)*K + k0 + q4*8;
      *(short8*)(&sBh[col*BSTR + q4*8]) = *(const short8*)(Bh + gof);
      *(short8*)(&sBl[col*BSTR + q4*8]) = *(const short8*)(Bl + gof);
    }
    short8 ah[2], al[2];
    #pragma unroll
    for (int g = 0; g < 2; ++g){
      const float* Ap = g ? Ap1 : Ap0;
      float4 a0 = *(const float4*)(Ap + k0);
      float4 a1 = *(const float4*)(Ap + k0 + 4);
      float av[8] = {a0.x,a0.y,a0.z,a0.w,a1.x,a1.y,a1.z,a1.w};
      #pragma unroll
      for (int j = 0; j < 8; ++j){
        unsigned short h = f2bf(av[j]);
        ah[g][j] = (short)h;
        al[g][j] = (short)f2bf(av[j] - bf2f(h));
      }
    }
    __syncthreads();
    #pragma unroll
    for (int s = 0; s < NSUB; ++s){
      int lof = (s*16 + l16)*BSTR + quad*8;
      short8 bh = *(const short8*)(&sBh[lof]);
      short8 bl = *(const short8*)(&sBl[lof]);
      #pragma unroll
      for (int g = 0; g < 2; ++g){
        acc[g][s] = __builtin_amdgcn_mfma_f32_16x16x32_bf16(ah[g], bh, acc[g][s], 0, 0, 0);
        acc[g][s] = __builtin_amdgcn_mfma_f32_16x16x32_bf16(al[g], bh, acc[g][s], 0, 0, 0);
        acc[g][s] = __builtin_amdgcn_mfma_f32_16x16x32_bf16(ah[g], bl, acc[g][s], 0, 0, 0);
      }
    }
    __syncthreads();
  }

  if (MODE == 1){
    #pragma unroll
    for (int g = 0; g < 2; ++g){
      #pragma unroll
      for (int s = 0; s < NSUB; ++s){
        int col = col0 + s*16 + l16;
        float bv = bias[col];
        #pragma unroll
        for (int r = 0; r < 4; ++r){
          int row = m0 + g*16 + quad*4 + r;
          if (row >= M) continue;
          float v = acc[g][s][r] + bv;
          int sel = col / 160, cc = col % 160;
          if (sel == 0)      C[(size_t)row*320 + cc] = v;
          else if (sel == 3) C[(size_t)row*320 + 160 + cc] = v;
          else {
            int h = cc/40, rem = cc%40, t = rem/10, j = rem%10;
            kv16[(size_t)row*384 + (size_t)(h*4+t)*24 + (sel==2?10:0) + j] = (_Float16)v;
          }
        }
      }
    }
  } else {
    // gate fuse: per-thread partial over its cols, reduce over l16, one atomic per row
    float pg[2][4];
    #pragma unroll
    for (int g = 0; g < 2; ++g)
      #pragma unroll
      for (int r = 0; r < 4; ++r) pg[g][r] = 0.f;
    #pragma unroll
    for (int s = 0; s < NSUB; ++s){
      int col = col0 + s*16 + l16;
      float bv = bias[col], wg = Wg2[col];
      #pragma unroll
      for (int g = 0; g < 2; ++g)
        #pragma unroll
        for (int r = 0; r < 4; ++r)
          pg[g][r] += fmaxf(acc[g][s][r] + bv, 0.f) * wg;
    }
    #pragma unroll
    for (int g = 0; g < 2; ++g)
      #pragma unroll
      for (int r = 0; r < 4; ++r){
        float v = pg[g][r];
        v += __shfl_xor(v, 1); v += __shfl_xor(v, 2);
        v += __shfl_xor(v, 4); v += __shfl_xor(v, 8);
        int row = m0 + g*16 + quad*4 + r;
        if (l16 == 0 && row < M) atomicAdd(&gate[row], v);
      }
  }
}

// ---------------- fused edge attention + beta gate ----------------
// wave = 4 edge-slots x (4 heads x 4 quarter-lanes); slot row = 24 fp16 {k10,v10,pad4} = 48B
// pipeline: meta 3-deep, kv 2-deep
__global__ __launch_bounds__(256) void k_attn(const float* __restrict__ qr,
                                              const _Float16* __restrict__ kv16,
                                              const float4* __restrict__ eattr,
                                              const int* __restrict__ esrc,
                                              const int* __restrict__ starts,
                                              const float* __restrict__ We, const float* __restrict__ be,
                                              const float* __restrict__ Wb,
                                              float* __restrict__ xc, int loff, int N){
  int n = blockIdx.x*4 + (threadIdx.x >> 6);
  if (n >= N) return;
  int lane = threadIdx.x & 63;
  int g4 = lane >> 4;
  int w  = lane & 15;
  int hh = w & 3, t = w >> 2;
  int cbase = DHEAD*hh + 10*t;
  int slot = hh*4 + t;
  const float scale = 0.15811388300841898f;  // 1/sqrt(40)

  float qs[10];
  const float* qp = qr + (size_t)n*320 + cbase;
  #pragma unroll
  for (int j = 0; j < 10; ++j) qs[j] = qp[j] * scale;

  float qw0=0.f,qw1=0.f,qw2=0.f,qw3=0.f,qb=0.f;
  #pragma unroll
  for (int j = 0; j < 10; ++j){
    int c = cbase + j;
    qw0 += qs[j]*We[c];     qw1 += qs[j]*We[160+c];
    qw2 += qs[j]*We[320+c]; qw3 += qs[j]*We[480+c];
    qb  += qs[j]*be[c];
  }
  qw0 += __shfl_xor(qw0,4); qw0 += __shfl_xor(qw0,8);
  qw1 += __shfl_xor(qw1,4); qw1 += __shfl_xor(qw1,8);
  qw2 += __shfl_xor(qw2,4); qw2 += __shfl_xor(qw2,8);
  qw3 += __shfl_xor(qw3,4); qw3 += __shfl_xor(qw3,8);
  qb  += __shfl_xor(qb ,4); qb  += __shfl_xor(qb ,8);

  float m = -INFINITY, ssum = 0.f;
  float acc[10];
  #pragma unroll
  for (int j = 0; j < 10; ++j) acc[j] = 0.f;
  float sa0=0.f, sa1=0.f, sa2=0.f, sa3=0.f;

  int st = starts[n], en = starts[n+1];
  int B = (en - st + 3) >> 2;

  int snA=0, snB=0, snC=0;
  float4 eaA, eaB, eaC;
  eaA = make_float4(0.f,0.f,0.f,0.f); eaB = eaA; eaC = eaA;
  bool vA=false, vB=false, vC=false;
  {
    int p0 = st + g4;      vA = (p0 < en); if (vA){ snA = esrc[p0]; eaA = eattr[p0]; }
    int p1 = st + 4 + g4;  vB = (p1 < en); if (vB){ snB = esrc[p1]; eaB = eattr[p1]; }
    int p2 = st + 8 + g4;  vC = (p2 < en); if (vC){ snC = esrc[p2]; eaC = eattr[p2]; }
  }
  float4 K00, K01, K02, K10, K11, K12;
  if (vA){
    const float4* kp = (const float4*)(kv16 + (size_t)snA*384 + (size_t)slot*24);
    K00 = kp[0]; K01 = kp[1]; K02 = kp[2];
  }
  if (vB){
    const float4* kp = (const float4*)(kv16 + (size_t)snB*384 + (size_t)slot*24);
    K10 = kp[0]; K11 = kp[1]; K12 = kp[2];
  }

  for (int b = 0; b < B; ++b){
    // meta for b+3
    int snD = 0; float4 eaD = make_float4(0.f,0.f,0.f,0.f); bool vD;
    int p3 = st + (b+3)*4 + g4;
    vD = (p3 < en); if (vD){ snD = esrc[p3]; eaD = eattr[p3]; }
    // kv for b+2 (meta C loaded 1 iter ago)
    float4 N0, N1, N2;
    if (vC){
      const float4* kp = (const float4*)(kv16 + (size_t)snC*384 + (size_t)slot*24);
      N0 = kp[0]; N1 = kp[1]; N2 = kp[2];
    }
    // compute batch b from K0x / eaA / vA
    union U { float4 f4; _Float16 h[8]; };
    U u0, u1, u2; u0.f4 = K00; u1.f4 = K01; u2.f4 = K02;
    float ck[10], cv[10];
    #pragma unroll
    for (int j = 0; j < 8; ++j) ck[j] = (float)u0.h[j];
    ck[8] = (float)u1.h[0]; ck[9] = (float)u1.h[1];
    #pragma unroll
    for (int j = 0; j < 6; ++j) cv[j] = (float)u1.h[2+j];
    #pragma unroll
    for (int j = 0; j < 4; ++j) cv[6+j] = (float)u2.h[j];

    float p = 0.f;
    if (vA){
      #pragma unroll
      for (int j = 0; j < 10; ++j) p += qs[j]*ck[j];
    }
    p += __shfl_xor(p, 4);
    p += __shfl_xor(p, 8);
    p += qb + eaA.x*qw0 + eaA.y*qw1 + eaA.z*qw2 + eaA.w*qw3;

    if (vA){
      float mnew = fmaxf(m, p);
      float fac = expf(m - mnew);
      float ex  = expf(p - mnew);
      ssum = ssum*fac + ex;
      #pragma unroll
      for (int j = 0; j < 10; ++j) acc[j] = acc[j]*fac + ex*cv[j];
      sa0 = sa0*fac + ex*eaA.x; sa1 = sa1*fac + ex*eaA.y;
      sa2 = sa2*fac + ex*eaA.z; sa3 = sa3*fac + ex*eaA.w;
      m = mnew;
    }
    // rotate pipeline
    snA = snB; eaA = eaB; vA = vB;
    snB = snC; eaB = eaC; vB = vC;
    snC = snD; eaC = eaD; vC = vD;
    K00 = K10; K01 = K11; K02 = K12;
    K10 = N0;  K11 = N1;  K12 = N2;
  }

  #pragma unroll
  for (int xm = 16; xm < 64; xm <<= 1){
    float mo = __shfl_xor(m, xm);
    float so = __shfl_xor(ssum, xm);
    float ao[10];
    #pragma unroll
    for (int j = 0; j < 10; ++j) ao[j] = __shfl_xor(acc[j], xm);
    float t0 = __shfl_xor(sa0, xm), t1 = __shfl_xor(sa1, xm);
    float t2 = __shfl_xor(sa2, xm), t3 = __shfl_xor(sa3, xm);
    float M2 = fmaxf(m, mo);
    float f1 = (m  == -INFINITY) ? 0.f : expf(m  - M2);
    float f2 = (mo == -INFINITY) ? 0.f : expf(mo - M2);
    ssum = ssum*f1 + so*f2;
    #pragma unroll
    for (int j = 0; j < 10; ++j) acc[j] = acc[j]*f1 + ao[j]*f2;
    sa0 = sa0*f1 + t0*f2; sa1 = sa1*f1 + t1*f2;
    sa2 = sa2*f1 + t2*f2; sa3 = sa3*f1 + t3*f2;
    m = M2;
  }

  float inv = (ssum > 0.f) ? 1.f/ssum : 0.f;
  float w0 = sa0*inv, w1 = sa1*inv, w2 = sa2*inv, w3 = sa3*inv;
  float bterm = (ssum > 0.f) ? 1.f : 0.f;
  float outv[10], rr[10];
  const float* rp = qr + (size_t)n*320 + 160 + cbase;
  #pragma unroll
  for (int j = 0; j < 10; ++j){
    int c = cbase + j;
    outv[j] = acc[j]*inv + w0*We[c] + w1*We[160+c] + w2*We[320+c] + w3*We[480+c] + bterm*be[c];
    rr[j] = rp[j];
  }
  float part = 0.f;
  if (g4 == 0){
    #pragma unroll
    for (int j = 0; j < 10; ++j){
      int c = cbase + j;
      part += outv[j]*Wb[c] + rr[j]*Wb[160+c] + (outv[j]-rr[j])*Wb[320+c];
    }
  }
  #pragma unroll
  for (int xm = 1; xm < 64; xm <<= 1) part += __shfl_xor(part, xm);
  float beta = 1.f/(1.f + expf(-part));
  if (g4 == 0){
    float* dp = xc + (size_t)n*JKW + loff + cbase;
    #pragma unroll
    for (int j = 0; j < 10; ++j) dp[j] = beta*rr[j] + (1.f-beta)*outv[j];
  }
}

// ---------------- graph boundaries / pooling ----------------
__global__ __launch_bounds__(256) void k_gbound(const int* __restrict__ batch, int N, int* __restrict__ gs){
  int i = blockIdx.x*256 + threadIdx.x;
  if (i >= N) return;
  int g = batch[i];
  int prev = (i == 0) ? -1 : batch[i-1];
  for (int gg = prev+1; gg <= g; ++gg) gs[gg] = i;
  if (i == N-1){ for (int gg = g+1; gg <= NGRAPH; ++gg) gs[gg] = N; }
}

__global__ __launch_bounds__(256) void k_gstat(const float* __restrict__ gate, const int* __restrict__ gs,
                                               float* __restrict__ gmax, float* __restrict__ gden){
  __shared__ float sm[256];
  int g = blockIdx.x, tid = threadIdx.x;
  int lo = gs[g], hi = gs[g+1];
  float m = -INFINITY;
  for (int i = lo + tid; i < hi; i += 256) m = fmaxf(m, gate[i]);
  sm[tid] = m; __syncthreads();
  for (int off = 128; off; off >>= 1){ if (tid < off) sm[tid] = fmaxf(sm[tid], sm[tid+off]); __syncthreads(); }
  float M = sm[0]; __syncthreads();
  float s = 0.f;
  for (int i = lo + tid; i < hi; i += 256) s += expf(gate[i] - M);
  sm[tid] = s; __syncthreads();
  for (int off = 128; off; off >>= 1){ if (tid < off) sm[tid] += sm[tid+off]; __syncthreads(); }
  if (tid == 0){ gmax[g] = M; gden[g] = sm[0]; }
}

__global__ __launch_bounds__(256) void k_att(const float* __restrict__ gate, const int* __restrict__ batch,
                                             const float* __restrict__ gmax, const float* __restrict__ gden,
                                             float* __restrict__ att, int N){
  int i = blockIdx.x*256 + threadIdx.x;
  if (i >= N) return;
  int g = batch[i];
  float d = gden[g];
  att[i] = (d > 0.f) ? expf(gate[i] - gmax[g])/d : 0.f;
}

__global__ __launch_bounds__(320) void k_pool(const float* __restrict__ xc, const float* __restrict__ att,
                                              const int* __restrict__ gs, float* __restrict__ pooled){
  int g = blockIdx.x, part = blockIdx.y, j = threadIdx.x;
  int lo = gs[g], hi = gs[g+1];
  int len = hi - lo;
  if (len <= 0) return;
  int chunk = (len + (int)gridDim.y - 1) / (int)gridDim.y;
  int a = lo + part*chunk;
  int bnd = a + chunk; if (bnd > hi) bnd = hi;
  if (a >= bnd) return;
  float s = 0.f;
  for (int n = a; n < bnd; ++n) s += att[n]*xc[(size_t)n*JKW + j];
  atomicAdd(&pooled[g*JKW + j], s);
}

__global__ __launch_bounds__(320) void k_head(const float* __restrict__ pooled, const float* __restrict__ Wh1,
                                              const float* __restrict__ bh1, const float* __restrict__ Wh2,
                                              const float* __restrict__ bh2, float* __restrict__ out){
  __shared__ float p[320];
  __shared__ float t[320];
  int g = blockIdx.x, tid = threadIdx.x;
  p[tid] = pooled[g*JKW + tid]; __syncthreads();
  float a = bh1[tid];
  for (int i = 0; i < 320; ++i) a += p[i]*Wh1[i*JKW + tid];
  t[tid] = fmaxf(a, 0.f); __syncthreads();
  if (tid < 6){
    float o = bh2[tid];
    for (int j = 0; j < 320; ++j) o += t[j]*Wh2[j*6 + tid];
    out[g*6 + tid] = o;
  }
}

extern "C" void kernel_launch(void* const* d_in, const int* in_sizes, int n_in,
                              void* d_out, int out_size, void* d_ws, size_t ws_size,
                              hipStream_t stream){
  (void)n_in; (void)out_size; (void)ws_size;
  const float* x        = (const float*)d_in[0];
  const int*   eidx     = (const int*)d_in[1];
  const float* edge_attr= (const float*)d_in[2];
  const int*   batch    = (const int*)d_in[3];
  const float* W_in     = (const float*)d_in[4];
  const float* b_in     = (const float*)d_in[5];
  const float* Wq       = (const float*)d_in[6];
  const float* bq       = (const float*)d_in[7];
  const float* Wk       = (const float*)d_in[8];
  const float* bk       = (const float*)d_in[9];
  const float* Wv       = (const float*)d_in[10];
  const float* bv       = (const float*)d_in[11];
  const float* We       = (const float*)d_in[12];
  const float* be       = (const float*)d_in[13];
  const float* Wsk      = (const float*)d_in[14];
  const float* bsk      = (const float*)d_in[15];
  const float* Wb       = (const float*)d_in[16];
  const float* Wg1      = (const float*)d_in[17];
  const float* bg1      = (const float*)d_in[18];
  const float* Wg2      = (const float*)d_in[19];
  const float* Wh1      = (const float*)d_in[21];
  const float* bh1      = (const float*)d_in[22];
  const float* Wh2      = (const float*)d_in[23];
  const float* bh2      = (const float*)d_in[24];

  const int N = in_sizes[0] / 5;
  const int E = in_sizes[1] / 2;
  float* out = (float*)d_out;

  char* w = (char*)d_ws;
  auto alloc = [&](size_t bytes)->char*{ char* p = w; w += (bytes + 255) & ~(size_t)255; return p; };
  float* xc     = (float*)alloc((size_t)N*JKW*4);
  float* qr     = (float*)alloc((size_t)N*320*4);          // q | skip(r), fp32
  _Float16* kv16= (_Float16*)alloc((size_t)N*384*2);       // 16 slots x {k10,v10,pad4} fp16
  unsigned short* Bth  = (unsigned short*)alloc((size_t)640*160*2);
  unsigned short* Btl  = (unsigned short*)alloc((size_t)640*160*2);
  unsigned short* Btgh = (unsigned short*)alloc((size_t)160*320*2);
  unsigned short* Btgl = (unsigned short*)alloc((size_t)160*320*2);
  float* bpack  = (float*)alloc(640*4);
  int*   deg    = (int*)alloc((size_t)N*4);
  int*   starts = (int*)alloc((size_t)(N+1)*4);
  int*   cursor = (int*)alloc((size_t)(N+1)*4);
  int*   esrc   = (int*)alloc((size_t)E*4);
  float4* eattr = (float4*)alloc((size_t)E*16);
  const int NB  = (N + 255)/256;
  int*   bsum   = (int*)alloc((size_t)NB*4);
  int*   boff   = (int*)alloc(256*4);
  float* gate   = (float*)alloc((size_t)N*4);
  float* attg   = (float*)alloc((size_t)N*4);
  int*   gs     = (int*)alloc((NGRAPH+1)*4);
  float* gmax   = (float*)alloc(NGRAPH*4);
  float* gden   = (float*)alloc(NGRAPH*4);
  float* pooled = (float*)alloc(NGRAPH*JKW*4);

  const int* srcI = eidx;
  const int* dstI = eidx + E;

  hipMemsetAsync(deg, 0, (size_t)N*4, stream);
  hipMemsetAsync(gate, 0, (size_t)N*4, stream);
  hipMemsetAsync(pooled, 0, (size_t)NGRAPH*JKW*4, stream);

  const int eb = (E + 255)/256;
  k_count<<<eb, 256, 0, stream>>>(dstI, E, deg);
  k_scan1<<<NB, 256, 0, stream>>>(deg, N, starts, bsum);
  k_scan2<<<1, 256, 0, stream>>>(bsum, NB, boff);
  k_scan3<<<NB, 256, 0, stream>>>(starts, cursor, boff, N, E);
  k_fill<<<eb, 256, 0, stream>>>(dstI, srcI, edge_attr, E, cursor, esrc, eattr);

  k_lin_in<<<(N*HIDW + 255)/256, 256, 0, stream>>>(x, W_in, b_in, xc, N);
  k_wpack_gate<<<200, 256, 0, stream>>>(Wg1, Btgh, Btgl);

  const int MB128 = (N + 127)/128;
  for (int l = 0; l < 2; ++l){
    k_wpack<<<400, 256, 0, stream>>>(Wq + l*25600, Wk + l*25600, Wv + l*25600, Wsk + l*25600,
                                     bq + l*160, bk + l*160, bv + l*160, bsk + l*160, Bth, Btl, bpack);
    dim3 g1(MB128, 5);
    k_mgemm<8,1><<<g1, 256, 0, stream>>>(xc, JKW, Bth, Btl, bpack, qr, kv16, nullptr, nullptr, N, HIDW);
    k_attn<<<(N + 3)/4, 256, 0, stream>>>(qr, kv16, eattr, esrc, starts,
                                          We + l*640, be + l*160, Wb + l*480, xc, l*HIDW, N);
  }

  // gate MLP fused: gate[n] = sum_col relu(xc@Wg1+bg1)[col]*Wg2[col]  (bg2 cancels in softmax)
  dim3 g2(MB128, 2);
  k_mgemm<5,2><<<g2, 256, 0, stream>>>(xc, JKW, Btgh, Btgl, bg1, nullptr, nullptr, Wg2, gate, N, JKW);

  k_gbound<<<(N + 255)/256, 256, 0, stream>>>(batch, N, gs);
  k_gstat<<<NGRAPH, 256, 0, stream>>>(gate, gs, gmax, gden);
  k_att<<<(N + 255)/256, 256, 0, stream>>>(gate, batch, gmax, gden, attg, N);
  dim3 g3(NGRAPH, 8);
  k_pool<<<g3, 320, 0, stream>>>(xc, attg, gs, pooled);
  k_head<<<NGRAPH, 320, 0, stream>>>(pooled, Wh1, bh1, Wh2, bh2, out);
}

// Round 8
// 720.966 us; speedup vs baseline: 1.4275x; 1.0235x over previous
//
#include <hip/hip_runtime.h>
#include <math.h>
#include <stddef.h>

#define NHEAD 4
#define DHEAD 40
#define HIDW 160
#define JKW 320
#define NGRAPH 32

typedef __attribute__((ext_vector_type(8))) short short8;
typedef __attribute__((ext_vector_type(4))) float f32x4;
typedef __fp16 h2 __attribute__((ext_vector_type(2)));

__device__ inline unsigned short f2bf(float x){
  unsigned u = __float_as_uint(x);
  u += 0x7fff + ((u >> 16) & 1);
  return (unsigned short)(u >> 16);
}
__device__ inline float fdot2(h2 a, h2 b, float c){
  return __builtin_amdgcn_fdot2(a, b, c, false);
}
__device__ inline h2 pk(float a, float b){
  return __builtin_amdgcn_cvt_pkrtz(a, b);
}
union HU { h2 h; int i; float f; };
__device__ inline h2 shfl_h2(h2 v, int xm){
  HU u; u.h = v; u.i = __shfl_xor(u.i, xm); return u.h;
}

// ---------------- CSR build ----------------
__global__ __launch_bounds__(256) void k_count(const int* __restrict__ dst, int E, int* __restrict__ deg){
  int e = blockIdx.x*256 + threadIdx.x;
  if (e < E) atomicAdd(&deg[dst[e]], 1);
}

__global__ __launch_bounds__(256) void k_scan1(const int* __restrict__ deg, int N, int* __restrict__ excl, int* __restrict__ bsum){
  __shared__ int s[256];
  int tid = threadIdx.x;
  int i = blockIdx.x*256 + tid;
  int v = (i < N) ? deg[i] : 0;
  s[tid] = v; __syncthreads();
  for (int off = 1; off < 256; off <<= 1){
    int t = (tid >= off) ? s[tid-off] : 0; __syncthreads();
    s[tid] += t; __syncthreads();
  }
  if (i < N) excl[i] = s[tid] - v;
  if (tid == 255) bsum[blockIdx.x] = s[255];
}

__global__ __launch_bounds__(256) void k_scan2(const int* __restrict__ bsum, int NB, int* __restrict__ boff){
  __shared__ int s[256];
  int tid = threadIdx.x;
  int v = (tid < NB) ? bsum[tid] : 0;
  s[tid] = v; __syncthreads();
  for (int off = 1; off < 256; off <<= 1){
    int t = (tid >= off) ? s[tid-off] : 0; __syncthreads();
    s[tid] += t; __syncthreads();
  }
  boff[tid] = s[tid] - v;
}

__global__ __launch_bounds__(256) void k_scan3(int* __restrict__ starts, int* __restrict__ cursor,
                                               const int* __restrict__ boff, int N, int E){
  int i = blockIdx.x*256 + threadIdx.x;
  if (i < N){
    int v = starts[i] + boff[blockIdx.x];
    starts[i] = v; cursor[i] = v;
  }
  if (i == 0) starts[N] = E;
}

// CSR fill: src id + fp16 edge_attr (8B) into CSR position
__global__ __launch_bounds__(256) void k_fill(const int* __restrict__ dst, const int* __restrict__ src,
                                              const float* __restrict__ edge_attr, int E,
                                              int* __restrict__ cursor, int* __restrict__ esrc,
                                              uint2* __restrict__ eattr){
  int e = blockIdx.x*256 + threadIdx.x;
  if (e < E){
    int d = dst[e];
    int p = atomicAdd(&cursor[d], 1);
    esrc[p] = src[e];
    float4 ea = *(const float4*)(edge_attr + (size_t)e*4);
    HU a, b; a.h = pk(ea.x, ea.y); b.h = pk(ea.z, ea.w);
    eattr[p] = make_uint2((unsigned)a.i, (unsigned)b.i);
  }
}

// ---------------- input linear ----------------
__global__ __launch_bounds__(256) void k_lin_in(const float* __restrict__ x, const float* __restrict__ W,
                                                const float* __restrict__ b, float* __restrict__ xc, int N){
  int idx = blockIdx.x*256 + threadIdx.x;
  if (idx >= N*HIDW) return;
  int n = idx / HIDW, j = idx % HIDW;
  const float* xr = x + n*5;
  float v = b[j];
  #pragma unroll
  for (int c = 0; c < 5; ++c) v += xr[c] * W[c*HIDW + j];
  xc[(size_t)n*JKW + j] = v;
}

// ---------------- weight pack (bf16 single) ----------------
__global__ __launch_bounds__(256) void k_wpack(const float* __restrict__ Wq, const float* __restrict__ Wk,
                                               const float* __restrict__ Wv, const float* __restrict__ Ws,
                                               const float* __restrict__ bq, const float* __restrict__ bk,
                                               const float* __restrict__ bv, const float* __restrict__ bs,
                                               unsigned short* __restrict__ Bth, float* __restrict__ bp){
  int idx = blockIdx.x*256 + threadIdx.x;
  if (idx < 640*160){
    int j = idx / 160, i = idx % 160;
    int sel = j / HIDW, jj = j % HIDW;
    const float* W = (sel==0) ? Wq : (sel==1) ? Wk : (sel==2) ? Wv : Ws;
    Bth[(size_t)j*160 + i] = f2bf(W[i*HIDW + jj]);
  }
  if (idx < 640){
    int sel = idx / HIDW, jj = idx % HIDW;
    const float* bb = (sel==0) ? bq : (sel==1) ? bk : (sel==2) ? bv : bs;
    bp[idx] = bb[jj];
  }
}

__global__ __launch_bounds__(256) void k_wpack_gate(const float* __restrict__ Wg1,
                                                    unsigned short* __restrict__ Bth){
  int idx = blockIdx.x*256 + threadIdx.x;
  if (idx >= 160*320) return;
  int j = idx / 320, i = idx % 320;
  Bth[(size_t)j*320 + i] = f2bf(Wg1[(size_t)i*160 + j]);
}

// ---------------- bf16 MFMA GEMM: 128-row block, 32 rows/wave, single MFMA ----------------
// MODE 1 (QKV remap): cols 0..159 -> qr[row][col]; 480..639 -> qr[row][160+cc];
//                     160..479 -> fp16 kv16[row][(h*4+t)*24 + (v?10:0)+j], row stride 384
// MODE 2 (gate fuse): v = relu(acc+bg1[col]); atomicAdd(gate[row], sum_col v*Wg2[col])
#define BSTR 40
template<int NSUB, int MODE>
__global__ __launch_bounds__(256) void k_mgemm(const float* __restrict__ A, int lda,
                                               const unsigned short* __restrict__ Bh,
                                               const float* __restrict__ bias,
                                               float* __restrict__ C,
                                               _Float16* __restrict__ kv16,
                                               const float* __restrict__ Wg2,
                                               float* __restrict__ gate,
                                               int M, int K){
  __shared__ short sBh[16*NSUB*BSTR];
  int tid = threadIdx.x;
  int wv = tid >> 6, lane = tid & 63;
  int quad = lane >> 4, l16 = lane & 15;
  int m0 = blockIdx.x*128 + wv*32;
  int col0 = blockIdx.y * (16*NSUB);
  int ar0 = m0 + l16;      if (ar0 >= M) ar0 = M - 1;
  int ar1 = m0 + 16 + l16; if (ar1 >= M) ar1 = M - 1;
  const float* Ap0 = A + (size_t)ar0*lda + quad*8;
  const float* Ap1 = A + (size_t)ar1*lda + quad*8;

  f32x4 acc[2][NSUB];
  #pragma unroll
  for (int g = 0; g < 2; ++g)
    #pragma unroll
    for (int s = 0; s < NSUB; ++s) acc[g][s] = (f32x4){0.f,0.f,0.f,0.f};

  for (int k0 = 0; k0 < K; k0 += 32){
    for (int u = tid; u < 16*NSUB*4; u += 256){
      int col = u >> 2, q4 = u & 3;
      size_t gof = (size_t)(col0 + col)*K + k0 + q4*8;
      *(short8*)(&sBh[col*BSTR + q4*8]) = *(const short8*)(Bh + gof);
    }
    short8 ah[2];
    #pragma unroll
    for (int g = 0; g < 2; ++g){
      const float* Ap = g ? Ap1 : Ap0;
      float4 a0 = *(const float4*)(Ap + k0);
      float4 a1 = *(const float4*)(Ap + k0 + 4);
      float av[8] = {a0.x,a0.y,a0.z,a0.w,a1.x,a1.y,a1.z,a1.w};
      #pragma unroll
      for (int j = 0; j < 8; ++j) ah[g][j] = (short)f2bf(av[j]);
    }
    __syncthreads();
    #pragma unroll
    for (int s = 0; s < NSUB; ++s){
      int lof = (s*16 + l16)*BSTR + quad*8;
      short8 bh = *(const short8*)(&sBh[lof]);
      #pragma unroll
      for (int g = 0; g < 2; ++g)
        acc[g][s] = __builtin_amdgcn_mfma_f32_16x16x32_bf16(ah[g], bh, acc[g][s], 0, 0, 0);
    }
    __syncthreads();
  }

  if (MODE == 1){
    #pragma unroll
    for (int g = 0; g < 2; ++g){
      #pragma unroll
      for (int s = 0; s < NSUB; ++s){
        int col = col0 + s*16 + l16;
        float bv = bias[col];
        #pragma unroll
        for (int r = 0; r < 4; ++r){
          int row = m0 + g*16 + quad*4 + r;
          if (row >= M) continue;
          float v = acc[g][s][r] + bv;
          int sel = col / 160, cc = col % 160;
          if (sel == 0)      C[(size_t)row*320 + cc] = v;
          else if (sel == 3) C[(size_t)row*320 + 160 + cc] = v;
          else {
            int h = cc/40, rem = cc%40, t = rem/10, j = rem%10;
            kv16[(size_t)row*384 + (size_t)(h*4+t)*24 + (sel==2?10:0) + j] = (_Float16)v;
          }
        }
      }
    }
  } else {
    float pg[2][4];
    #pragma unroll
    for (int g = 0; g < 2; ++g)
      #pragma unroll
      for (int r = 0; r < 4; ++r) pg[g][r] = 0.f;
    #pragma unroll
    for (int s = 0; s < NSUB; ++s){
      int col = col0 + s*16 + l16;
      float bv = bias[col], wg = Wg2[col];
      #pragma unroll
      for (int g = 0; g < 2; ++g)
        #pragma unroll
        for (int r = 0; r < 4; ++r)
          pg[g][r] += fmaxf(acc[g][s][r] + bv, 0.f) * wg;
    }
    #pragma unroll
    for (int g = 0; g < 2; ++g)
      #pragma unroll
      for (int r = 0; r < 4; ++r){
        float v = pg[g][r];
        v += __shfl_xor(v, 1); v += __shfl_xor(v, 2);
        v += __shfl_xor(v, 4); v += __shfl_xor(v, 8);
        int row = m0 + g*16 + quad*4 + r;
        if (l16 == 0 && row < M) atomicAdd(&gate[row], v);
      }
  }
}

// ---------------- fused edge attention + beta gate (packed fp16 math) ----------------
// wave = 4 edge-slots x (4 heads x 4 quarter-lanes); slot row = 24 fp16 {k10,v10,pad4} = 48B
__global__ __launch_bounds__(256) void k_attn(const float* __restrict__ qr,
                                              const _Float16* __restrict__ kv16,
                                              const uint2* __restrict__ eattr,
                                              const int* __restrict__ esrc,
                                              const int* __restrict__ starts,
                                              const float* __restrict__ We, const float* __restrict__ be,
                                              const float* __restrict__ Wb,
                                              float* __restrict__ xc, int loff, int N){
  int n = blockIdx.x*4 + (threadIdx.x >> 6);
  if (n >= N) return;
  int lane = threadIdx.x & 63;
  int g4 = lane >> 4;
  int w  = lane & 15;
  int hh = w & 3, t = w >> 2;
  int cbase = DHEAD*hh + 10*t;
  int slot = hh*4 + t;
  const float scale = 0.15811388300841898f;  // 1/sqrt(40)

  const float* qp = qr + (size_t)n*320 + cbase;
  float qsf[10];
  #pragma unroll
  for (int j = 0; j < 10; ++j) qsf[j] = qp[j] * scale;
  h2 qh[5];
  #pragma unroll
  for (int i = 0; i < 5; ++i) qh[i] = pk(qsf[2*i], qsf[2*i+1]);

  float qw0=0.f,qw1=0.f,qw2=0.f,qw3=0.f,qb=0.f;
  #pragma unroll
  for (int j = 0; j < 10; ++j){
    int c = cbase + j;
    qw0 += qsf[j]*We[c];     qw1 += qsf[j]*We[160+c];
    qw2 += qsf[j]*We[320+c]; qw3 += qsf[j]*We[480+c];
    qb  += qsf[j]*be[c];
  }
  qw0 += __shfl_xor(qw0,4); qw0 += __shfl_xor(qw0,8);
  qw1 += __shfl_xor(qw1,4); qw1 += __shfl_xor(qw1,8);
  qw2 += __shfl_xor(qw2,4); qw2 += __shfl_xor(qw2,8);
  qw3 += __shfl_xor(qw3,4); qw3 += __shfl_xor(qw3,8);
  qb  += __shfl_xor(qb ,4); qb  += __shfl_xor(qb ,8);
  h2 qw01 = pk(qw0, qw1), qw23 = pk(qw2, qw3);

  float m = -INFINITY, ssum = 0.f;
  h2 acch[5], sah[2];
  h2 zh = pk(0.f, 0.f);
  #pragma unroll
  for (int i = 0; i < 5; ++i) acch[i] = zh;
  sah[0] = zh; sah[1] = zh;

  int st = starts[n], en = starts[n+1];
  int B = (en - st + 3) >> 2;

  // pipeline: meta 2-deep, kv 1-deep
  int snA = 0, snB = 0; bool vA = false, vB = false;
  h2 eaA0 = zh, eaA1 = zh, eaB0 = zh, eaB1 = zh;
  {
    int p0 = st + g4;
    vA = (p0 < en);
    if (vA){ snA = esrc[p0]; uint2 e = eattr[p0]; HU a,b; a.i=(int)e.x; b.i=(int)e.y; eaA0=a.h; eaA1=b.h; }
    int p1 = st + 4 + g4;
    vB = (p1 < en);
    if (vB){ snB = esrc[p1]; uint2 e = eattr[p1]; HU a,b; a.i=(int)e.x; b.i=(int)e.y; eaB0=a.h; eaB1=b.h; }
  }
  float4 c0, c1, c2;
  if (vA){
    const float4* kp = (const float4*)(kv16 + (size_t)snA*384 + (size_t)slot*24);
    c0 = kp[0]; c1 = kp[1]; c2 = kp[2];
  }

  for (int b = 0; b < B; ++b){
    // meta b+2
    int snC = 0; h2 eaC0 = zh, eaC1 = zh; bool vC;
    int p2 = st + (b+2)*4 + g4;
    vC = (p2 < en);
    if (vC){ snC = esrc[p2]; uint2 e = eattr[p2]; HU a,b2; a.i=(int)e.x; b2.i=(int)e.y; eaC0=a.h; eaC1=b2.h; }
    // kv for b+1
    float4 n0, n1, n2;
    if (vB){
      const float4* kp = (const float4*)(kv16 + (size_t)snB*384 + (size_t)slot*24);
      n0 = kp[0]; n1 = kp[1]; n2 = kp[2];
    }
    // compute batch b
    union { float4 f4; h2 p[4]; } u0, u1, u2;
    u0.f4 = c0; u1.f4 = c1; u2.f4 = c2;
    float p = 0.f;
    if (vA){
      p = fdot2(qh[0], u0.p[0], p);
      p = fdot2(qh[1], u0.p[1], p);
      p = fdot2(qh[2], u0.p[2], p);
      p = fdot2(qh[3], u0.p[3], p);
      p = fdot2(qh[4], u1.p[0], p);
    }
    p += __shfl_xor(p, 4);
    p += __shfl_xor(p, 8);
    p += qb;
    p = fdot2(eaA0, qw01, p);
    p = fdot2(eaA1, qw23, p);

    if (vA){
      float mnew = fmaxf(m, p);
      float fac = expf(m - mnew);
      float ex  = expf(p - mnew);
      ssum = ssum*fac + ex;
      h2 fh = pk(fac, fac), eh = pk(ex, ex);
      acch[0] = acch[0]*fh + u1.p[1]*eh;
      acch[1] = acch[1]*fh + u1.p[2]*eh;
      acch[2] = acch[2]*fh + u1.p[3]*eh;
      acch[3] = acch[3]*fh + u2.p[0]*eh;
      acch[4] = acch[4]*fh + u2.p[1]*eh;
      sah[0] = sah[0]*fh + eaA0*eh;
      sah[1] = sah[1]*fh + eaA1*eh;
      m = mnew;
    }
    // rotate
    snA = snB; eaA0 = eaB0; eaA1 = eaB1; vA = vB;
    snB = snC; eaB0 = eaC0; eaB1 = eaC1; vB = vC;
    c0 = n0; c1 = n1; c2 = n2;
  }

  // merge the 4 edge-slots (xor 16, 32)
  #pragma unroll
  for (int xm = 16; xm < 64; xm <<= 1){
    float mo = __shfl_xor(m, xm);
    float so = __shfl_xor(ssum, xm);
    h2 ao[5], so2[2];
    #pragma unroll
    for (int i = 0; i < 5; ++i) ao[i] = shfl_h2(acch[i], xm);
    so2[0] = shfl_h2(sah[0], xm); so2[1] = shfl_h2(sah[1], xm);
    float M2 = fmaxf(m, mo);
    float f1 = (m  == -INFINITY) ? 0.f : expf(m  - M2);
    float f2 = (mo == -INFINITY) ? 0.f : expf(mo - M2);
    ssum = ssum*f1 + so*f2;
    h2 f1h = pk(f1, f1), f2h = pk(f2, f2);
    #pragma unroll
    for (int i = 0; i < 5; ++i) acch[i] = acch[i]*f1h + ao[i]*f2h;
    sah[0] = sah[0]*f1h + so2[0]*f2h;
    sah[1] = sah[1]*f1h + so2[1]*f2h;
    m = M2;
  }

  float inv = (ssum > 0.f) ? 1.f/ssum : 0.f;
  float w0 = (float)sah[0].x*inv, w1 = (float)sah[0].y*inv;
  float w2 = (float)sah[1].x*inv, w3 = (float)sah[1].y*inv;
  float bterm = (ssum > 0.f) ? 1.f : 0.f;
  float accf[10];
  #pragma unroll
  for (int i = 0; i < 5; ++i){ accf[2*i] = (float)acch[i].x; accf[2*i+1] = (float)acch[i].y; }
  float outv[10], rr[10];
  const float* rp = qr + (size_t)n*320 + 160 + cbase;
  #pragma unroll
  for (int j = 0; j < 10; ++j){
    int c = cbase + j;
    outv[j] = accf[j]*inv + w0*We[c] + w1*We[160+c] + w2*We[320+c] + w3*We[480+c] + bterm*be[c];
    rr[j] = rp[j];
  }
  float part = 0.f;
  if (g4 == 0){
    #pragma unroll
    for (int j = 0; j < 10; ++j){
      int c = cbase + j;
      part += outv[j]*Wb[c] + rr[j]*Wb[160+c] + (outv[j]-rr[j])*Wb[320+c];
    }
  }
  #pragma unroll
  for (int xm = 1; xm < 64; xm <<= 1) part += __shfl_xor(part, xm);
  float beta = 1.f/(1.f + expf(-part));
  if (g4 == 0){
    float* dp = xc + (size_t)n*JKW + loff + cbase;
    #pragma unroll
    for (int j = 0; j < 10; ++j) dp[j] = beta*rr[j] + (1.f-beta)*outv[j];
  }
}

// ---------------- graph boundaries / pooling ----------------
__global__ __launch_bounds__(256) void k_gbound(const int* __restrict__ batch, int N, int* __restrict__ gs){
  int i = blockIdx.x*256 + threadIdx.x;
  if (i >= N) return;
  int g = batch[i];
  int prev = (i == 0) ? -1 : batch[i-1];
  for (int gg = prev+1; gg <= g; ++gg) gs[gg] = i;
  if (i == N-1){ for (int gg = g+1; gg <= NGRAPH; ++gg) gs[gg] = N; }
}

__global__ __launch_bounds__(256) void k_gstat(const float* __restrict__ gate, const int* __restrict__ gs,
                                               float* __restrict__ gmax, float* __restrict__ gden){
  __shared__ float sm[256];
  int g = blockIdx.x, tid = threadIdx.x;
  int lo = gs[g], hi = gs[g+1];
  float m = -INFINITY;
  for (int i = lo + tid; i < hi; i += 256) m = fmaxf(m, gate[i]);
  sm[tid] = m; __syncthreads();
  for (int off = 128; off; off >>= 1){ if (tid < off) sm[tid] = fmaxf(sm[tid], sm[tid+off]); __syncthreads(); }
  float M = sm[0]; __syncthreads();
  float s = 0.f;
  for (int i = lo + tid; i < hi; i += 256) s += expf(gate[i] - M);
  sm[tid] = s; __syncthreads();
  for (int off = 128; off; off >>= 1){ if (tid < off) sm[tid] += sm[tid+off]; __syncthreads(); }
  if (tid == 0){ gmax[g] = M; gden[g] = sm[0]; }
}

__global__ __launch_bounds__(256) void k_att(const float* __restrict__ gate, const int* __restrict__ batch,
                                             const float* __restrict__ gmax, const float* __restrict__ gden,
                                             float* __restrict__ att, int N){
  int i = blockIdx.x*256 + threadIdx.x;
  if (i >= N) return;
  int g = batch[i];
  float d = gden[g];
  att[i] = (d > 0.f) ? expf(gate[i] - gmax[g])/d : 0.f;
}

__global__ __launch_bounds__(320) void k_pool(const float* __restrict__ xc, const float* __restrict__ att,
                                              const int* __restrict__ gs, float* __restrict__ pooled){
  int g = blockIdx.x, part = blockIdx.y, j = threadIdx.x;
  int lo = gs[g], hi = gs[g+1];
  int len = hi - lo;
  if (len <= 0) return;
  int chunk = (len + (int)gridDim.y - 1) / (int)gridDim.y;
  int a = lo + part*chunk;
  int bnd = a + chunk; if (bnd > hi) bnd = hi;
  if (a >= bnd) return;
  float s = 0.f;
  for (int n = a; n < bnd; ++n) s += att[n]*xc[(size_t)n*JKW + j];
  atomicAdd(&pooled[g*JKW + j], s);
}

__global__ __launch_bounds__(320) void k_head(const float* __restrict__ pooled, const float* __restrict__ Wh1,
                                              const float* __restrict__ bh1, const float* __restrict__ Wh2,
                                              const float* __restrict__ bh2, float* __restrict__ out){
  __shared__ float p[320];
  __shared__ float t[320];
  int g = blockIdx.x, tid = threadIdx.x;
  p[tid] = pooled[g*JKW + tid]; __syncthreads();
  float a = bh1[tid];
  for (int i = 0; i < 320; ++i) a += p[i]*Wh1[i*JKW + tid];
  t[tid] = fmaxf(a, 0.f); __syncthreads();
  if (tid < 6){
    float o = bh2[tid];
    for (int j = 0; j < 320; ++j) o += t[j]*Wh2[j*6 + tid];
    out[g*6 + tid] = o;
  }
}

extern "C" void kernel_launch(void* const* d_in, const int* in_sizes, int n_in,
                              void* d_out, int out_size, void* d_ws, size_t ws_size,
                              hipStream_t stream){
  (void)n_in; (void)out_size; (void)ws_size;
  const float* x        = (const float*)d_in[0];
  const int*   eidx     = (const int*)d_in[1];
  const float* edge_attr= (const float*)d_in[2];
  const int*   batch    = (const int*)d_in[3];
  const float* W_in     = (const float*)d_in[4];
  const float* b_in     = (const float*)d_in[5];
  const float* Wq       = (const float*)d_in[6];
  const float* bq       = (const float*)d_in[7];
  const float* Wk       = (const float*)d_in[8];
  const float* bk       = (const float*)d_in[9];
  const float* Wv       = (const float*)d_in[10];
  const float* bv       = (const float*)d_in[11];
  const float* We       = (const float*)d_in[12];
  const float* be       = (const float*)d_in[13];
  const float* Wsk      = (const float*)d_in[14];
  const float* bsk      = (const float*)d_in[15];
  const float* Wb       = (const float*)d_in[16];
  const float* Wg1      = (const float*)d_in[17];
  const float* bg1      = (const float*)d_in[18];
  const float* Wg2      = (const float*)d_in[19];
  const float* Wh1      = (const float*)d_in[21];
  const float* bh1      = (const float*)d_in[22];
  const float* Wh2      = (const float*)d_in[23];
  const float* bh2      = (const float*)d_in[24];

  const int N = in_sizes[0] / 5;
  const int E = in_sizes[1] / 2;
  float* out = (float*)d_out;

  char* w = (char*)d_ws;
  auto alloc = [&](size_t bytes)->char*{ char* p = w; w += (bytes + 255) & ~(size_t)255; return p; };
  float* xc     = (float*)alloc((size_t)N*JKW*4);
  float* qr     = (float*)alloc((size_t)N*320*4);          // q | skip(r), fp32
  _Float16* kv16= (_Float16*)alloc((size_t)N*384*2);       // 16 slots x {k10,v10,pad4} fp16
  unsigned short* Bth  = (unsigned short*)alloc((size_t)640*160*2);
  unsigned short* Btgh = (unsigned short*)alloc((size_t)160*320*2);
  float* bpack  = (float*)alloc(640*4);
  int*   deg    = (int*)alloc((size_t)N*4);
  int*   starts = (int*)alloc((size_t)(N+1)*4);
  int*   cursor = (int*)alloc((size_t)(N+1)*4);
  int*   esrc   = (int*)alloc((size_t)E*4);
  uint2* eattr  = (uint2*)alloc((size_t)E*8);
  const int NB  = (N + 255)/256;
  int*   bsum   = (int*)alloc((size_t)NB*4);
  int*   boff   = (int*)alloc(256*4);
  float* gate   = (float*)alloc((size_t)N*4);
  float* attg   = (float*)alloc((size_t)N*4);
  int*   gs     = (int*)alloc((NGRAPH+1)*4);
  float* gmax   = (float*)alloc(NGRAPH*4);
  float* gden   = (float*)alloc(NGRAPH*4);
  float* pooled = (float*)alloc(NGRAPH*JKW*4);

  const int* srcI = eidx;
  const int* dstI = eidx + E;

  hipMemsetAsync(deg, 0, (size_t)N*4, stream);
  hipMemsetAsync(gate, 0, (size_t)N*4, stream);
  hipMemsetAsync(pooled, 0, (size_t)NGRAPH*JKW*4, stream);

  const int eb = (E + 255)/256;
  k_count<<<eb, 256, 0, stream>>>(dstI, E, deg);
  k_scan1<<<NB, 256, 0, stream>>>(deg, N, starts, bsum);
  k_scan2<<<1, 256, 0, stream>>>(bsum, NB, boff);
  k_scan3<<<NB, 256, 0, stream>>>(starts, cursor, boff, N, E);
  k_fill<<<eb, 256, 0, stream>>>(dstI, srcI, edge_attr, E, cursor, esrc, eattr);

  k_lin_in<<<(N*HIDW + 255)/256, 256, 0, stream>>>(x, W_in, b_in, xc, N);
  k_wpack_gate<<<200, 256, 0, stream>>>(Wg1, Btgh);

  const int MB128 = (N + 127)/128;
  for (int l = 0; l < 2; ++l){
    k_wpack<<<400, 256, 0, stream>>>(Wq + l*25600, Wk + l*25600, Wv + l*25600, Wsk + l*25600,
                                     bq + l*160, bk + l*160, bv + l*160, bsk + l*160, Bth, bpack);
    dim3 g1(MB128, 5);
    k_mgemm<8,1><<<g1, 256, 0, stream>>>(xc, JKW, Bth, bpack, qr, kv16, nullptr, nullptr, N, HIDW);
    k_attn<<<(N + 3)/4, 256, 0, stream>>>(qr, kv16, eattr, esrc, starts,
                                          We + l*640, be + l*160, Wb + l*480, xc, l*HIDW, N);
  }

  // gate MLP fused: gate[n] = sum_col relu(xc@Wg1+bg1)[col]*Wg2[col]  (bg2 cancels in softmax)
  dim3 g2(MB128, 2);
  k_mgemm<5,2><<<g2, 256, 0, stream>>>(xc, JKW, Btgh, bg1, nullptr, nullptr, Wg2, gate, N, JKW);

  k_gbound<<<(N + 255)/256, 256, 0, stream>>>(batch, N, gs);
  k_gstat<<<NGRAPH, 256, 0, stream>>>(gate, gs, gmax, gden);
  k_att<<<(N + 255)/256, 256, 0, stream>>>(gate, batch, gmax, gden, attg, N);
  dim3 g3(NGRAPH, 8);
  k_pool<<<g3, 320, 0, stream>>>(xc, attg, gs, pooled);
  k_head<<<NGRAPH, 320, 0, stream>>>(pooled, Wh1, bh1, Wh2, bh2, out);
}